// Round 3
// baseline (724.511 us; speedup 1.0000x reference)
//
#include <hip/hip_runtime.h>

#define N_NODES 50000
#define N_EDGES 800000
#define D_IN 128
#define D_OUT 128
#define N_TYPES 4
#define LN_EPS 1e-5f
#define N_BUCKETS (N_TYPES * N_NODES)   // 200000
#define SCAN_T 1024
#define NJT 9                            // 8 w1 halves + 1 self

typedef __attribute__((ext_vector_type(4))) float f32x4;
typedef __attribute__((ext_vector_type(8))) __bf16 bf16x8;
typedef __attribute__((ext_vector_type(8))) unsigned short u16x8;

// ---- workspace layout (bytes), 256-aligned sections ----
constexpr size_t wsal(size_t x) { return (x + 255) & ~size_t(255); }
constexpr size_t OFF_CNT   = 0;                                              // 200000*4
constexpr size_t OFF_PTR   = OFF_CNT  + wsal((size_t)N_BUCKETS * 4);         // 200001*4
constexpr size_t OFF_CUR   = OFF_PTR  + wsal((size_t)(N_BUCKETS + 1) * 4);
constexpr size_t OFF_SROWS = OFF_CUR  + wsal((size_t)N_BUCKETS * 4);         // 800000*4
constexpr size_t OFF_XB    = OFF_SROWS + wsal((size_t)N_EDGES * 4);          // 12.8MB
constexpr size_t OFF_WCAT  = OFF_XB   + wsal((size_t)N_NODES * D_IN * 2);    // 9*4*128*32*2
constexpr size_t OFF_BIAS  = OFF_WCAT + wsal((size_t)NJT * 4 * 128 * 32 * 2);
constexpr size_t OFF_W2T   = OFF_BIAS + wsal((size_t)NJT * 128 * 4);
constexpr size_t OFF_XABC  = OFF_W2T  + wsal((size_t)N_TYPES * 4 * 128 * 32 * 2);
constexpr size_t OFF_S     = OFF_XABC + wsal((size_t)N_NODES * NJT * 128 * 2);  // 115.2MB
constexpr size_t WS_TOTAL  = OFF_S    + wsal((size_t)N_BUCKETS * 128 * 2);      // +51.2MB ≈ 185MB

__device__ __forceinline__ unsigned short f2bf(float f) {
    unsigned int u = __builtin_bit_cast(unsigned int, f);
    u += 0x7FFFu + ((u >> 16) & 1u);   // RNE; inputs finite
    return (unsigned short)(u >> 16);
}
__device__ __forceinline__ float bf2f_lo(unsigned int u) { return __builtin_bit_cast(float, u << 16); }
__device__ __forceinline__ float bf2f_hi(unsigned int u) { return __builtin_bit_cast(float, u & 0xFFFF0000u); }

// ---------------- prep kernels ----------------
__global__ void k_cvt_x(const float* __restrict__ x, unsigned short* __restrict__ xb) {
    int i = blockIdx.x * blockDim.x + threadIdx.x;
    if (i * 4 >= N_NODES * D_IN) return;
    const float4 v = reinterpret_cast<const float4*>(x)[i];
    ushort4 o;
    o.x = f2bf(v.x); o.y = f2bf(v.y); o.z = f2bf(v.z); o.w = f2bf(v.w);
    reinterpret_cast<ushort4*>(xb)[i] = o;
}

// wcatT[jt][ks][jm][kk] = Wcat[ks*32+kk][jt*128+jm]; jt<8: w1[t=jt>>1][(jt&1)*128 + k][jm], jt==8: sw[k][jm]
__global__ void k_prep_wcat(const float* __restrict__ w1, const float* __restrict__ sw,
                            unsigned short* __restrict__ wcatT) {
    int gid = blockIdx.x * blockDim.x + threadIdx.x;
    if (gid >= NJT * 4 * 128 * 32) return;
    int kk = gid & 31;
    int jm = (gid >> 5) & 127;
    int ks = (gid >> 12) & 3;
    int jt = gid >> 14;
    int k  = ks * 32 + kk;
    float v;
    if (jt < 8) {
        int t = jt >> 1, half = jt & 1;
        v = w1[((size_t)t * 256 + half * 128 + k) * 128 + jm];
    } else {
        v = sw[(size_t)k * 128 + jm];
    }
    wcatT[gid] = f2bf(v);
}

__global__ void k_prep_bias(const float* __restrict__ b1, const float* __restrict__ sb,
                            float* __restrict__ bias) {
    int gid = blockIdx.x * blockDim.x + threadIdx.x;
    if (gid >= NJT * 128) return;
    int jt = gid >> 7, jm = gid & 127;
    float v = 0.f;
    if (jt < 8) { if (jt & 1) v = b1[(jt >> 1) * 128 + jm]; }
    else v = sb[jm];
    bias[gid] = v;
}

// w2T[t][ks][f][kk] = w2[t][ks*32+kk][f]
__global__ void k_prep_w2(const float* __restrict__ w2, unsigned short* __restrict__ w2T) {
    int gid = blockIdx.x * blockDim.x + threadIdx.x;
    if (gid >= N_TYPES * 4 * 128 * 32) return;
    int kk = gid & 31;
    int f  = (gid >> 5) & 127;
    int ks = (gid >> 12) & 3;
    int t  = gid >> 14;
    float v = w2[((size_t)t * 128 + ks * 32 + kk) * 128 + f];
    w2T[gid] = f2bf(v);
}

// ---------------- (type, col) counting sort ----------------
__global__ void k_hist2(const int* __restrict__ ei, const int* __restrict__ attr,
                        int* __restrict__ cnt) {
    int e = blockIdx.x * blockDim.x + threadIdx.x;
    if (e >= N_EDGES) return;
    int t = attr[e];
    int c = ei[N_EDGES + e];
    atomicAdd(&cnt[t * N_NODES + c], 1);
}

__global__ __launch_bounds__(SCAN_T) void k_scan2(const int* __restrict__ cnt,
                                                  int* __restrict__ ptr,
                                                  int* __restrict__ cursor) {
    __shared__ int part[SCAN_T];
    const int tid = threadIdx.x;
    const int CH = (N_BUCKETS + SCAN_T - 1) / SCAN_T;
    const int s0 = min(tid * CH, N_BUCKETS), s1 = min(s0 + CH, N_BUCKETS);
    int sum = 0;
    for (int i = s0; i < s1; ++i) sum += cnt[i];
    part[tid] = sum;
    __syncthreads();
    for (int d = 1; d < SCAN_T; d <<= 1) {
        int v = (tid >= d) ? part[tid - d] : 0;
        __syncthreads();
        part[tid] += v;
        __syncthreads();
    }
    int run = (tid > 0) ? part[tid - 1] : 0;
    for (int i = s0; i < s1; ++i) {
        ptr[i] = run; cursor[i] = run;
        run += cnt[i];
    }
    if (tid == SCAN_T - 1) ptr[N_BUCKETS] = run;
}

// srows[pos] = source-row of the edge, grouped by (type, col)
__global__ void k_scatter2(const int* __restrict__ ei, const int* __restrict__ attr,
                           int* __restrict__ cursor, int* __restrict__ srows) {
    int e = blockIdx.x * blockDim.x + threadIdx.x;
    if (e >= N_EDGES) return;
    int t = attr[e];
    int c = ei[N_EDGES + e];
    int pos = atomicAdd(&cursor[t * N_NODES + c], 1);
    srows[pos] = ei[e];
}

// ---------------- GEMM1: XABC[n][j] = xb[n] @ Wcat[:,j] + bias[j]  (bf16 out, 50000 x 1152) ----------------
__global__ __launch_bounds__(256, 2) void k_gemm1(
    const unsigned short* __restrict__ xb,
    const unsigned short* __restrict__ wcatT,
    const float* __restrict__ bias,
    unsigned short* __restrict__ xabc)
{
    const int nb = blockIdx.x * 128;
    const int jt = blockIdx.y;

    __shared__ __align__(16) unsigned short sX[128 * 136];  // x rows [n][k], pad 136; reused as out tile [n][j]
    __shared__ __align__(16) unsigned short sW[128 * 32];   // WcatT chunk [j][kk]

    const int tid = threadIdx.x;
    const int lane = tid & 63;
    const int w = tid >> 6;
    const int g = lane >> 4;
    const int c = lane & 15;
    const int wf = w >> 1;   // j half
    const int we = w & 1;    // n half

    // stage x rows (coalesced; clamp OOB rows)
    #pragma unroll
    for (int it = 0; it < 8; ++it) {
        int row = 16 * it + (tid >> 4);
        int node = min(nb + row, N_NODES - 1);
        const u16x8 v = *reinterpret_cast<const u16x8*>(xb + (size_t)node * D_IN + (tid & 15) * 8);
        *reinterpret_cast<u16x8*>(&sX[row * 136 + (tid & 15) * 8]) = v;
    }

    f32x4 acc[4][4];
    #pragma unroll
    for (int ft = 0; ft < 4; ++ft)
        #pragma unroll
        for (int et = 0; et < 4; ++et)
            acc[ft][et] = f32x4{0.f, 0.f, 0.f, 0.f};

    for (int ks = 0; ks < 4; ++ks) {
        __syncthreads();   // covers x staging (ks=0) and prior reads
        {
            const u16x8* gsrc = reinterpret_cast<const u16x8*>(wcatT + (size_t)(jt * 4 + ks) * 4096);
            u16x8* ldst = reinterpret_cast<u16x8*>(sW);
            ldst[tid] = gsrc[tid];
            ldst[tid + 256] = gsrc[tid + 256];
        }
        __syncthreads();
        bf16x8 af[4], bfr[4];
        #pragma unroll
        for (int ft = 0; ft < 4; ++ft)
            af[ft] = *reinterpret_cast<const bf16x8*>(&sW[(64 * wf + 16 * ft + c) * 32 + 8 * g]);
        #pragma unroll
        for (int et = 0; et < 4; ++et)
            bfr[et] = *reinterpret_cast<const bf16x8*>(&sX[(64 * we + 16 * et + c) * 136 + ks * 32 + 8 * g]);
        #pragma unroll
        for (int ft = 0; ft < 4; ++ft)
            #pragma unroll
            for (int et = 0; et < 4; ++et)
                acc[ft][et] = __builtin_amdgcn_mfma_f32_16x16x32_bf16(af[ft], bfr[et], acc[ft][et], 0, 0, 0);
    }
    __syncthreads();   // sX reads done; reuse as output tile

    // + bias, pack bf16 -> sX as [n][j] (u32 pairs)
    {
        float bv[4][4];
        #pragma unroll
        for (int ft = 0; ft < 4; ++ft)
            #pragma unroll
            for (int r = 0; r < 4; ++r)
                bv[ft][r] = bias[jt * 128 + 64 * wf + 16 * ft + 4 * g + r];
        unsigned int* so = reinterpret_cast<unsigned int*>(sX);
        #pragma unroll
        for (int ft = 0; ft < 4; ++ft) {
            #pragma unroll
            for (int et = 0; et < 4; ++et) {
                int n = 64 * we + 16 * et + c;
                int jb = 32 * wf + 8 * ft + 2 * g;   // u32 index within row
                float v0 = acc[ft][et][0] + bv[ft][0];
                float v1 = acc[ft][et][1] + bv[ft][1];
                float v2 = acc[ft][et][2] + bv[ft][2];
                float v3 = acc[ft][et][3] + bv[ft][3];
                so[n * 68 + jb + 0] = (unsigned int)f2bf(v0) | ((unsigned int)f2bf(v1) << 16);
                so[n * 68 + jb + 1] = (unsigned int)f2bf(v2) | ((unsigned int)f2bf(v3) << 16);
            }
        }
    }
    __syncthreads();

    // coalesced write to XABC
    #pragma unroll
    for (int it = 0; it < 8; ++it) {
        int row = 16 * it + (tid >> 4);
        int node = nb + row;
        if (node < N_NODES) {
            const u16x8 v = *reinterpret_cast<const u16x8*>(&sX[row * 136 + (tid & 15) * 8]);
            *reinterpret_cast<u16x8*>(xabc + (size_t)node * (NJT * 128) + jt * 128 + (tid & 15) * 8) = v;
        }
    }
}

// ---------------- bucket aggregation: S[t*N+n] = sum_{e in (t,n)} relu(XA_t[row_e] + XB_t[n]) ----------------
__global__ void k_bucket(const unsigned short* __restrict__ xabc,
                         const int* __restrict__ ptr,
                         const int* __restrict__ srows,
                         unsigned short* __restrict__ S)
{
    const int b = blockIdx.x * 4 + (threadIdx.x >> 6);
    if (b >= N_BUCKETS) return;
    const int lane = threadIdx.x & 63;
    const int t = b / N_NODES;
    const int n = b - t * N_NODES;
    const int s = ptr[b], e = ptr[b + 1];
    const unsigned int* x32 = reinterpret_cast<const unsigned int*>(xabc);
    float a0 = 0.f, a1 = 0.f;
    if (s < e) {
        const unsigned int xbv = x32[(size_t)n * 576 + (2 * t + 1) * 64 + lane];  // XB_t[n] (+b1 baked)
        const float xb0 = bf2f_lo(xbv), xb1 = bf2f_hi(xbv);
        for (int j = s; j < e; ++j) {
            int row = srows[j];
            unsigned int va = x32[(size_t)row * 576 + 2 * t * 64 + lane];          // XA_t[row]
            a0 += fmaxf(bf2f_lo(va) + xb0, 0.f);
            a1 += fmaxf(bf2f_hi(va) + xb1, 0.f);
        }
    }
    reinterpret_cast<unsigned int*>(S)[(size_t)b * 64 + lane] =
        (unsigned int)f2bf(a0) | ((unsigned int)f2bf(a1) << 16);
}

// ---------------- GEMM2: out[n][f] = XC[n][f] + sum_t S_t[n] @ W2_t[:,f] + sum_t cnt_{t,n} * b2_t[f] ----------------
__global__ __launch_bounds__(256, 2) void k_gemm2(
    const unsigned short* __restrict__ S,
    const unsigned short* __restrict__ w2T,
    const float* __restrict__ b2,
    const unsigned short* __restrict__ xabc,
    const int* __restrict__ ptr,
    float* __restrict__ out)
{
    const int nb = blockIdx.x * 128;
    __shared__ __align__(16) unsigned short sS[128 * 136];    // S rows for current type
    __shared__ __align__(16) unsigned short sW2[4 * 128 * 32]; // full W2T for current type (32KB)
    __shared__ float sB2[N_TYPES * 128];

    const int tid = threadIdx.x;
    const int lane = tid & 63;
    const int w = tid >> 6;
    const int g = lane >> 4;
    const int c = lane & 15;
    const int wf = w >> 1;   // f half
    const int we = w & 1;    // n half

    sB2[tid] = b2[tid];
    sB2[tid + 256] = b2[tid + 256];

    f32x4 acc[4][4];
    #pragma unroll
    for (int ft = 0; ft < 4; ++ft)
        #pragma unroll
        for (int et = 0; et < 4; ++et)
            acc[ft][et] = f32x4{0.f, 0.f, 0.f, 0.f};

    for (int t = 0; t < N_TYPES; ++t) {
        __syncthreads();   // prev reads done before restage
        // stage S tile (coalesced, clamp)
        #pragma unroll
        for (int it = 0; it < 8; ++it) {
            int row = 16 * it + (tid >> 4);
            int bidx = t * N_NODES + min(nb + row, N_NODES - 1);
            const u16x8 v = *reinterpret_cast<const u16x8*>(S + (size_t)bidx * 128 + (tid & 15) * 8);
            *reinterpret_cast<u16x8*>(&sS[row * 136 + (tid & 15) * 8]) = v;
        }
        // stage full W2T[t] (linear copy)
        {
            const u16x8* gsrc = reinterpret_cast<const u16x8*>(w2T + (size_t)t * 16384);
            u16x8* ldst = reinterpret_cast<u16x8*>(sW2);
            #pragma unroll
            for (int it = 0; it < 8; ++it)
                ldst[tid + 256 * it] = gsrc[tid + 256 * it];
        }
        __syncthreads();
        #pragma unroll
        for (int ks = 0; ks < 4; ++ks) {
            bf16x8 af[4], bfr[4];
            #pragma unroll
            for (int ft = 0; ft < 4; ++ft)
                af[ft] = *reinterpret_cast<const bf16x8*>(&sW2[ks * 4096 + (64 * wf + 16 * ft + c) * 32 + 8 * g]);
            #pragma unroll
            for (int et = 0; et < 4; ++et)
                bfr[et] = *reinterpret_cast<const bf16x8*>(&sS[(64 * we + 16 * et + c) * 136 + ks * 32 + 8 * g]);
            #pragma unroll
            for (int ft = 0; ft < 4; ++ft)
                #pragma unroll
                for (int et = 0; et < 4; ++et)
                    acc[ft][et] = __builtin_amdgcn_mfma_f32_16x16x32_bf16(af[ft], bfr[et], acc[ft][et], 0, 0, 0);
        }
    }
    __syncthreads();

    // epilogue: + XC + cnt*b2, write fp32
    const unsigned int* x32 = reinterpret_cast<const unsigned int*>(xabc);
    #pragma unroll
    for (int et = 0; et < 4; ++et) {
        int n = 64 * we + 16 * et + c;
        int node = nb + n;
        if (node >= N_NODES) continue;
        float cnt4[N_TYPES];
        #pragma unroll
        for (int t = 0; t < N_TYPES; ++t)
            cnt4[t] = (float)(ptr[t * N_NODES + node + 1] - ptr[t * N_NODES + node]);
        #pragma unroll
        for (int ft = 0; ft < 4; ++ft) {
            int f0 = 64 * wf + 16 * ft + 4 * g;
            unsigned int xc0 = x32[(size_t)node * 576 + 512 + (f0 >> 1)];
            unsigned int xc1 = x32[(size_t)node * 576 + 512 + (f0 >> 1) + 1];
            float v[4];
            v[0] = acc[ft][et][0] + bf2f_lo(xc0);
            v[1] = acc[ft][et][1] + bf2f_hi(xc0);
            v[2] = acc[ft][et][2] + bf2f_lo(xc1);
            v[3] = acc[ft][et][3] + bf2f_hi(xc1);
            #pragma unroll
            for (int r = 0; r < 4; ++r) {
                float bs = 0.f;
                #pragma unroll
                for (int t = 0; t < N_TYPES; ++t)
                    bs = fmaf(cnt4[t], sB2[t * 128 + f0 + r], bs);
                v[r] += bs;
            }
            *reinterpret_cast<float4*>(out + (size_t)node * D_OUT + f0) = *reinterpret_cast<float4*>(v);
        }
    }
}

// ---------------- ReLU + LayerNorm (in-place on out), one wave per node ----------------
__global__ __launch_bounds__(256) void k_ln(float* __restrict__ out,
                                            const float* __restrict__ gamma,
                                            const float* __restrict__ beta)
{
    const int node = blockIdx.x * 4 + (threadIdx.x >> 6);
    const int lane = threadIdx.x & 63;
    float2 v = *reinterpret_cast<float2*>(out + (size_t)node * D_OUT + lane * 2);
    v.x = fmaxf(v.x, 0.f);
    v.y = fmaxf(v.y, 0.f);
    float s = v.x + v.y;
    float ss = v.x * v.x + v.y * v.y;
    #pragma unroll
    for (int m = 1; m < 64; m <<= 1) {
        s  += __shfl_xor(s, m, 64);
        ss += __shfl_xor(ss, m, 64);
    }
    float mu = s * (1.f / 128.f);
    float var = ss * (1.f / 128.f) - mu * mu;
    float rs = rsqrtf(var + LN_EPS);
    const float2 gm = *reinterpret_cast<const float2*>(gamma + lane * 2);
    const float2 bt = *reinterpret_cast<const float2*>(beta + lane * 2);
    float2 o;
    o.x = (v.x - mu) * rs * gm.x + bt.x;
    o.y = (v.y - mu) * rs * gm.y + bt.y;
    *reinterpret_cast<float2*>(out + (size_t)node * D_OUT + lane * 2) = o;
}

extern "C" void kernel_launch(void* const* d_in, const int* in_sizes, int n_in,
                              void* d_out, int out_size, void* d_ws, size_t ws_size,
                              hipStream_t stream) {
    const float* x     = (const float*)d_in[0];
    const int*   ei    = (const int*)d_in[1];
    const int*   attr  = (const int*)d_in[2];
    const float* w1    = (const float*)d_in[3];
    const float* b1    = (const float*)d_in[4];
    const float* w2    = (const float*)d_in[5];
    const float* b2    = (const float*)d_in[6];
    const float* sw    = (const float*)d_in[7];
    const float* sb    = (const float*)d_in[8];
    const float* gamma = (const float*)d_in[9];
    const float* beta  = (const float*)d_in[10];
    float* out = (float*)d_out;

    if (ws_size < WS_TOTAL) return;   // fail visibly rather than corrupt (round-2 proved >=225MB)

    char* ws = (char*)d_ws;
    int* cnt    = (int*)(ws + OFF_CNT);
    int* ptr    = (int*)(ws + OFF_PTR);
    int* cursor = (int*)(ws + OFF_CUR);
    int* srows  = (int*)(ws + OFF_SROWS);
    unsigned short* xb    = (unsigned short*)(ws + OFF_XB);
    unsigned short* wcatT = (unsigned short*)(ws + OFF_WCAT);
    float*          bias  = (float*)(ws + OFF_BIAS);
    unsigned short* w2T   = (unsigned short*)(ws + OFF_W2T);
    unsigned short* xabc  = (unsigned short*)(ws + OFF_XABC);
    unsigned short* S     = (unsigned short*)(ws + OFF_S);

    hipMemsetAsync(cnt, 0, (size_t)N_BUCKETS * 4, stream);

    k_cvt_x<<<(N_NODES * D_IN / 4 + 255) / 256, 256, 0, stream>>>(x, xb);
    k_prep_wcat<<<(NJT * 4 * 128 * 32 + 255) / 256, 256, 0, stream>>>(w1, sw, wcatT);
    k_prep_bias<<<(NJT * 128 + 255) / 256, 256, 0, stream>>>(b1, sb, bias);
    k_prep_w2<<<(N_TYPES * 4 * 128 * 32 + 255) / 256, 256, 0, stream>>>(w2, w2T);

    k_hist2<<<(N_EDGES + 255) / 256, 256, 0, stream>>>(ei, attr, cnt);
    k_scan2<<<1, SCAN_T, 0, stream>>>(cnt, ptr, cursor);
    k_scatter2<<<(N_EDGES + 255) / 256, 256, 0, stream>>>(ei, attr, cursor, srows);

    k_gemm1<<<dim3((N_NODES + 127) / 128, NJT), 256, 0, stream>>>(xb, wcatT, bias, xabc);
    k_bucket<<<(N_BUCKETS + 3) / 4, 256, 0, stream>>>(xabc, ptr, srows, S);
    k_gemm2<<<(N_NODES + 127) / 128, 256, 0, stream>>>(S, w2T, b2, xabc, ptr, out);
    k_ln<<<N_NODES / 4, 256, 0, stream>>>(out, gamma, beta);
}

// Round 4
// 290.881 us; speedup vs baseline: 2.4908x; 2.4908x over previous
//
#include <hip/hip_runtime.h>

#define N_NODES 50000
#define N_EDGES 800000
#define D_IN 128
#define D_OUT 128
#define N_TYPES 4
#define LN_EPS 1e-5f
#define N_BUCKETS (N_TYPES * N_NODES)   // 200000
#define NJT 9                            // 8 w1 halves + 1 self
#define SB_ITEMS 1024
#define NSB ((N_BUCKETS + SB_ITEMS - 1) / SB_ITEMS)   // 196

typedef __attribute__((ext_vector_type(4))) float f32x4;
typedef __attribute__((ext_vector_type(8))) __bf16 bf16x8;
typedef __attribute__((ext_vector_type(8))) unsigned short u16x8;

// ---- workspace layout (bytes), 256-aligned sections ----
constexpr size_t wsal(size_t x) { return (x + 255) & ~size_t(255); }
constexpr size_t OFF_CNT   = 0;                                              // 200000*4
constexpr size_t OFF_PTR   = OFF_CNT  + wsal((size_t)N_BUCKETS * 4);         // 200001*4
constexpr size_t OFF_CUR   = OFF_PTR  + wsal((size_t)(N_BUCKETS + 1) * 4);
constexpr size_t OFF_BSUM  = OFF_CUR  + wsal((size_t)N_BUCKETS * 4);         // 256*4
constexpr size_t OFF_BOFF  = OFF_BSUM + wsal((size_t)256 * 4);
constexpr size_t OFF_SROWS = OFF_BOFF + wsal((size_t)256 * 4);               // 800000*4
constexpr size_t OFF_XB    = OFF_SROWS + wsal((size_t)N_EDGES * 4);          // 12.8MB
constexpr size_t OFF_WCAT  = OFF_XB   + wsal((size_t)N_NODES * D_IN * 2);    // 9*4*128*32*2
constexpr size_t OFF_BIAS  = OFF_WCAT + wsal((size_t)NJT * 4 * 128 * 32 * 2);
constexpr size_t OFF_W2T   = OFF_BIAS + wsal((size_t)NJT * 128 * 4);
constexpr size_t OFF_XABC  = OFF_W2T  + wsal((size_t)N_TYPES * 4 * 128 * 32 * 2);
constexpr size_t OFF_S     = OFF_XABC + wsal((size_t)N_NODES * NJT * 128 * 2);  // 115.2MB
constexpr size_t WS_TOTAL  = OFF_S    + wsal((size_t)N_BUCKETS * 128 * 2);      // +51.2MB ≈ 185MB

__device__ __forceinline__ unsigned short f2bf(float f) {
    unsigned int u = __builtin_bit_cast(unsigned int, f);
    u += 0x7FFFu + ((u >> 16) & 1u);   // RNE; inputs finite
    return (unsigned short)(u >> 16);
}
__device__ __forceinline__ float bf2f_lo(unsigned int u) { return __builtin_bit_cast(float, u << 16); }
__device__ __forceinline__ float bf2f_hi(unsigned int u) { return __builtin_bit_cast(float, u & 0xFFFF0000u); }

// ---------------- prep kernels ----------------
__global__ void k_cvt_x(const float* __restrict__ x, unsigned short* __restrict__ xb) {
    int i = blockIdx.x * blockDim.x + threadIdx.x;
    if (i * 4 >= N_NODES * D_IN) return;
    const float4 v = reinterpret_cast<const float4*>(x)[i];
    ushort4 o;
    o.x = f2bf(v.x); o.y = f2bf(v.y); o.z = f2bf(v.z); o.w = f2bf(v.w);
    reinterpret_cast<ushort4*>(xb)[i] = o;
}

// wcatT[jt][ks][jm][kk] = Wcat[ks*32+kk][jt*128+jm]; jt<8: w1[t=jt>>1][(jt&1)*128 + k][jm], jt==8: sw[k][jm]
__global__ void k_prep_wcat(const float* __restrict__ w1, const float* __restrict__ sw,
                            unsigned short* __restrict__ wcatT) {
    int gid = blockIdx.x * blockDim.x + threadIdx.x;
    if (gid >= NJT * 4 * 128 * 32) return;
    int kk = gid & 31;
    int jm = (gid >> 5) & 127;
    int ks = (gid >> 12) & 3;
    int jt = gid >> 14;
    int k  = ks * 32 + kk;
    float v;
    if (jt < 8) {
        int t = jt >> 1, half = jt & 1;
        v = w1[((size_t)t * 256 + half * 128 + k) * 128 + jm];
    } else {
        v = sw[(size_t)k * 128 + jm];
    }
    wcatT[gid] = f2bf(v);
}

__global__ void k_prep_bias(const float* __restrict__ b1, const float* __restrict__ sb,
                            float* __restrict__ bias) {
    int gid = blockIdx.x * blockDim.x + threadIdx.x;
    if (gid >= NJT * 128) return;
    int jt = gid >> 7, jm = gid & 127;
    float v = 0.f;
    if (jt < 8) { if (jt & 1) v = b1[(jt >> 1) * 128 + jm]; }
    else v = sb[jm];
    bias[gid] = v;
}

// w2T[t][ks][f][kk] = w2[t][ks*32+kk][f]
__global__ void k_prep_w2(const float* __restrict__ w2, unsigned short* __restrict__ w2T) {
    int gid = blockIdx.x * blockDim.x + threadIdx.x;
    if (gid >= N_TYPES * 4 * 128 * 32) return;
    int kk = gid & 31;
    int f  = (gid >> 5) & 127;
    int ks = (gid >> 12) & 3;
    int t  = gid >> 14;
    float v = w2[((size_t)t * 128 + ks * 32 + kk) * 128 + f];
    w2T[gid] = f2bf(v);
}

// ---------------- (type, col) counting sort ----------------
__global__ void k_hist2(const int* __restrict__ ei, const int* __restrict__ attr,
                        int* __restrict__ cnt) {
    int e = blockIdx.x * blockDim.x + threadIdx.x;
    if (e >= N_EDGES) return;
    int t = attr[e];
    int c = ei[N_EDGES + e];
    atomicAdd(&cnt[t * N_NODES + c], 1);
}

// ---- 3-phase device-wide exclusive scan over cnt[200000] ----
__global__ __launch_bounds__(256) void k_scanA(const int* __restrict__ cnt, int* __restrict__ bsum) {
    __shared__ int red[256];
    const int b = blockIdx.x, tid = threadIdx.x;
    const int base = b * SB_ITEMS + tid * 4;
    int s = 0;
    if (base + 3 < N_BUCKETS) {
        const int4 v = *reinterpret_cast<const int4*>(cnt + base);
        s = v.x + v.y + v.z + v.w;
    } else {
        #pragma unroll
        for (int i = 0; i < 4; ++i) if (base + i < N_BUCKETS) s += cnt[base + i];
    }
    red[tid] = s;
    __syncthreads();
    #pragma unroll
    for (int d = 128; d > 0; d >>= 1) {
        if (tid < d) red[tid] += red[tid + d];
        __syncthreads();
    }
    if (tid == 0) bsum[b] = red[0];
}

__global__ __launch_bounds__(256) void k_scanB(const int* __restrict__ bsum,
                                               int* __restrict__ boff,
                                               int* __restrict__ ptr) {
    __shared__ int sc[256];
    const int tid = threadIdx.x;
    int v = (tid < NSB) ? bsum[tid] : 0;
    sc[tid] = v;
    __syncthreads();
    #pragma unroll
    for (int d = 1; d < 256; d <<= 1) {
        int add = (tid >= d) ? sc[tid - d] : 0;
        __syncthreads();
        sc[tid] += add;
        __syncthreads();
    }
    if (tid < NSB) boff[tid] = sc[tid] - v;   // exclusive
    if (tid == 0) ptr[N_BUCKETS] = N_EDGES;   // total is a known constant
}

__global__ __launch_bounds__(256) void k_scanC(const int* __restrict__ cnt,
                                               const int* __restrict__ boff,
                                               int* __restrict__ ptr,
                                               int* __restrict__ cursor) {
    __shared__ int sc[256];
    const int b = blockIdx.x, tid = threadIdx.x;
    const int base = b * SB_ITEMS + tid * 4;
    int v[4] = {0, 0, 0, 0};
    if (base + 3 < N_BUCKETS) {
        const int4 t4 = *reinterpret_cast<const int4*>(cnt + base);
        v[0] = t4.x; v[1] = t4.y; v[2] = t4.z; v[3] = t4.w;
    } else {
        #pragma unroll
        for (int i = 0; i < 4; ++i) if (base + i < N_BUCKETS) v[i] = cnt[base + i];
    }
    const int s = v[0] + v[1] + v[2] + v[3];
    sc[tid] = s;
    __syncthreads();
    #pragma unroll
    for (int d = 1; d < 256; d <<= 1) {
        int add = (tid >= d) ? sc[tid - d] : 0;
        __syncthreads();
        sc[tid] += add;
        __syncthreads();
    }
    int run = boff[b] + sc[tid] - s;
    #pragma unroll
    for (int i = 0; i < 4; ++i) {
        if (base + i < N_BUCKETS) {
            ptr[base + i] = run;
            cursor[base + i] = run;
            run += v[i];
        }
    }
}

// srows[pos] = source-row of the edge, grouped by (type, col)
__global__ void k_scatter2(const int* __restrict__ ei, const int* __restrict__ attr,
                           int* __restrict__ cursor, int* __restrict__ srows) {
    int e = blockIdx.x * blockDim.x + threadIdx.x;
    if (e >= N_EDGES) return;
    int t = attr[e];
    int c = ei[N_EDGES + e];
    int pos = atomicAdd(&cursor[t * N_NODES + c], 1);
    srows[pos] = ei[e];
}

// ---------------- GEMM1: XABC[n][j] = xb[n] @ Wcat[:,j] + bias[j]  (bf16 out, 50000 x 1152) ----------------
__global__ __launch_bounds__(256, 2) void k_gemm1(
    const unsigned short* __restrict__ xb,
    const unsigned short* __restrict__ wcatT,
    const float* __restrict__ bias,
    unsigned short* __restrict__ xabc)
{
    const int nb = blockIdx.x * 128;
    const int jt = blockIdx.y;

    __shared__ __align__(16) unsigned short sX[128 * 136];  // x rows [n][k], pad 136; reused as out tile [n][j]
    __shared__ __align__(16) unsigned short sW[128 * 32];   // WcatT chunk [j][kk]

    const int tid = threadIdx.x;
    const int lane = tid & 63;
    const int w = tid >> 6;
    const int g = lane >> 4;
    const int c = lane & 15;
    const int wf = w >> 1;   // j half
    const int we = w & 1;    // n half

    // stage x rows (coalesced; clamp OOB rows)
    #pragma unroll
    for (int it = 0; it < 8; ++it) {
        int row = 16 * it + (tid >> 4);
        int node = min(nb + row, N_NODES - 1);
        const u16x8 v = *reinterpret_cast<const u16x8*>(xb + (size_t)node * D_IN + (tid & 15) * 8);
        *reinterpret_cast<u16x8*>(&sX[row * 136 + (tid & 15) * 8]) = v;
    }

    f32x4 acc[4][4];
    #pragma unroll
    for (int ft = 0; ft < 4; ++ft)
        #pragma unroll
        for (int et = 0; et < 4; ++et)
            acc[ft][et] = f32x4{0.f, 0.f, 0.f, 0.f};

    for (int ks = 0; ks < 4; ++ks) {
        __syncthreads();   // covers x staging (ks=0) and prior reads
        {
            const u16x8* gsrc = reinterpret_cast<const u16x8*>(wcatT + (size_t)(jt * 4 + ks) * 4096);
            u16x8* ldst = reinterpret_cast<u16x8*>(sW);
            ldst[tid] = gsrc[tid];
            ldst[tid + 256] = gsrc[tid + 256];
        }
        __syncthreads();
        bf16x8 af[4], bfr[4];
        #pragma unroll
        for (int ft = 0; ft < 4; ++ft)
            af[ft] = *reinterpret_cast<const bf16x8*>(&sW[(64 * wf + 16 * ft + c) * 32 + 8 * g]);
        #pragma unroll
        for (int et = 0; et < 4; ++et)
            bfr[et] = *reinterpret_cast<const bf16x8*>(&sX[(64 * we + 16 * et + c) * 136 + ks * 32 + 8 * g]);
        #pragma unroll
        for (int ft = 0; ft < 4; ++ft)
            #pragma unroll
            for (int et = 0; et < 4; ++et)
                acc[ft][et] = __builtin_amdgcn_mfma_f32_16x16x32_bf16(af[ft], bfr[et], acc[ft][et], 0, 0, 0);
    }
    __syncthreads();   // sX reads done; reuse as output tile

    // + bias, pack bf16 -> sX as [n][j] (u32 pairs)
    {
        float bv[4][4];
        #pragma unroll
        for (int ft = 0; ft < 4; ++ft)
            #pragma unroll
            for (int r = 0; r < 4; ++r)
                bv[ft][r] = bias[jt * 128 + 64 * wf + 16 * ft + 4 * g + r];
        unsigned int* so = reinterpret_cast<unsigned int*>(sX);
        #pragma unroll
        for (int ft = 0; ft < 4; ++ft) {
            #pragma unroll
            for (int et = 0; et < 4; ++et) {
                int n = 64 * we + 16 * et + c;
                int jb = 32 * wf + 8 * ft + 2 * g;   // u32 index within row
                float v0 = acc[ft][et][0] + bv[ft][0];
                float v1 = acc[ft][et][1] + bv[ft][1];
                float v2 = acc[ft][et][2] + bv[ft][2];
                float v3 = acc[ft][et][3] + bv[ft][3];
                so[n * 68 + jb + 0] = (unsigned int)f2bf(v0) | ((unsigned int)f2bf(v1) << 16);
                so[n * 68 + jb + 1] = (unsigned int)f2bf(v2) | ((unsigned int)f2bf(v3) << 16);
            }
        }
    }
    __syncthreads();

    // coalesced write to XABC
    #pragma unroll
    for (int it = 0; it < 8; ++it) {
        int row = 16 * it + (tid >> 4);
        int node = nb + row;
        if (node < N_NODES) {
            const u16x8 v = *reinterpret_cast<const u16x8*>(&sX[row * 136 + (tid & 15) * 8]);
            *reinterpret_cast<u16x8*>(xabc + (size_t)node * (NJT * 128) + jt * 128 + (tid & 15) * 8) = v;
        }
    }
}

// ---------------- bucket aggregation: S[t*N+n] = sum_{e in (t,n)} relu(XA_t[row_e] + XB_t[n]) ----------------
__global__ void k_bucket(const unsigned short* __restrict__ xabc,
                         const int* __restrict__ ptr,
                         const int* __restrict__ srows,
                         unsigned short* __restrict__ S)
{
    const int b = blockIdx.x * 4 + (threadIdx.x >> 6);
    if (b >= N_BUCKETS) return;
    const int lane = threadIdx.x & 63;
    const int t = b / N_NODES;
    const int n = b - t * N_NODES;
    const int s = ptr[b], e = ptr[b + 1];
    const unsigned int* x32 = reinterpret_cast<const unsigned int*>(xabc);
    float a0 = 0.f, a1 = 0.f;
    if (s < e) {
        const unsigned int xbv = x32[(size_t)n * 576 + (2 * t + 1) * 64 + lane];  // XB_t[n] (+b1 baked)
        const float xb0 = bf2f_lo(xbv), xb1 = bf2f_hi(xbv);
        for (int j = s; j < e; ++j) {
            int row = srows[j];
            unsigned int va = x32[(size_t)row * 576 + 2 * t * 64 + lane];          // XA_t[row]
            a0 += fmaxf(bf2f_lo(va) + xb0, 0.f);
            a1 += fmaxf(bf2f_hi(va) + xb1, 0.f);
        }
    }
    reinterpret_cast<unsigned int*>(S)[(size_t)b * 64 + lane] =
        (unsigned int)f2bf(a0) | ((unsigned int)f2bf(a1) << 16);
}

// ---------------- GEMM2: out[n][f] = XC[n][f] + sum_t S_t[n] @ W2_t[:,f] + sum_t cnt_{t,n} * b2_t[f] ----------------
__global__ __launch_bounds__(256, 2) void k_gemm2(
    const unsigned short* __restrict__ S,
    const unsigned short* __restrict__ w2T,
    const float* __restrict__ b2,
    const unsigned short* __restrict__ xabc,
    const int* __restrict__ ptr,
    float* __restrict__ out)
{
    const int nb = blockIdx.x * 128;
    __shared__ __align__(16) unsigned short sS[128 * 136];    // S rows for current type
    __shared__ __align__(16) unsigned short sW2[4 * 128 * 32]; // full W2T for current type (32KB)
    __shared__ float sB2[N_TYPES * 128];

    const int tid = threadIdx.x;
    const int lane = tid & 63;
    const int w = tid >> 6;
    const int g = lane >> 4;
    const int c = lane & 15;
    const int wf = w >> 1;   // f half
    const int we = w & 1;    // n half

    sB2[tid] = b2[tid];
    sB2[tid + 256] = b2[tid + 256];

    f32x4 acc[4][4];
    #pragma unroll
    for (int ft = 0; ft < 4; ++ft)
        #pragma unroll
        for (int et = 0; et < 4; ++et)
            acc[ft][et] = f32x4{0.f, 0.f, 0.f, 0.f};

    for (int t = 0; t < N_TYPES; ++t) {
        __syncthreads();   // prev reads done before restage
        // stage S tile (coalesced, clamp)
        #pragma unroll
        for (int it = 0; it < 8; ++it) {
            int row = 16 * it + (tid >> 4);
            int bidx = t * N_NODES + min(nb + row, N_NODES - 1);
            const u16x8 v = *reinterpret_cast<const u16x8*>(S + (size_t)bidx * 128 + (tid & 15) * 8);
            *reinterpret_cast<u16x8*>(&sS[row * 136 + (tid & 15) * 8]) = v;
        }
        // stage full W2T[t] (linear copy)
        {
            const u16x8* gsrc = reinterpret_cast<const u16x8*>(w2T + (size_t)t * 16384);
            u16x8* ldst = reinterpret_cast<u16x8*>(sW2);
            #pragma unroll
            for (int it = 0; it < 8; ++it)
                ldst[tid + 256 * it] = gsrc[tid + 256 * it];
        }
        __syncthreads();
        #pragma unroll
        for (int ks = 0; ks < 4; ++ks) {
            bf16x8 af[4], bfr[4];
            #pragma unroll
            for (int ft = 0; ft < 4; ++ft)
                af[ft] = *reinterpret_cast<const bf16x8*>(&sW2[ks * 4096 + (64 * wf + 16 * ft + c) * 32 + 8 * g]);
            #pragma unroll
            for (int et = 0; et < 4; ++et)
                bfr[et] = *reinterpret_cast<const bf16x8*>(&sS[(64 * we + 16 * et + c) * 136 + ks * 32 + 8 * g]);
            #pragma unroll
            for (int ft = 0; ft < 4; ++ft)
                #pragma unroll
                for (int et = 0; et < 4; ++et)
                    acc[ft][et] = __builtin_amdgcn_mfma_f32_16x16x32_bf16(af[ft], bfr[et], acc[ft][et], 0, 0, 0);
        }
    }
    __syncthreads();

    // epilogue: + XC + cnt*b2, write fp32
    const unsigned int* x32 = reinterpret_cast<const unsigned int*>(xabc);
    #pragma unroll
    for (int et = 0; et < 4; ++et) {
        int n = 64 * we + 16 * et + c;
        int node = nb + n;
        if (node >= N_NODES) continue;
        float cnt4[N_TYPES];
        #pragma unroll
        for (int t = 0; t < N_TYPES; ++t)
            cnt4[t] = (float)(ptr[t * N_NODES + node + 1] - ptr[t * N_NODES + node]);
        #pragma unroll
        for (int ft = 0; ft < 4; ++ft) {
            int f0 = 64 * wf + 16 * ft + 4 * g;
            unsigned int xc0 = x32[(size_t)node * 576 + 512 + (f0 >> 1)];
            unsigned int xc1 = x32[(size_t)node * 576 + 512 + (f0 >> 1) + 1];
            float v[4];
            v[0] = acc[ft][et][0] + bf2f_lo(xc0);
            v[1] = acc[ft][et][1] + bf2f_hi(xc0);
            v[2] = acc[ft][et][2] + bf2f_lo(xc1);
            v[3] = acc[ft][et][3] + bf2f_hi(xc1);
            #pragma unroll
            for (int r = 0; r < 4; ++r) {
                float bs = 0.f;
                #pragma unroll
                for (int t = 0; t < N_TYPES; ++t)
                    bs = fmaf(cnt4[t], sB2[t * 128 + f0 + r], bs);
                v[r] += bs;
            }
            *reinterpret_cast<float4*>(out + (size_t)node * D_OUT + f0) = *reinterpret_cast<float4*>(v);
        }
    }
}

// ---------------- ReLU + LayerNorm (in-place on out), one wave per node ----------------
__global__ __launch_bounds__(256) void k_ln(float* __restrict__ out,
                                            const float* __restrict__ gamma,
                                            const float* __restrict__ beta)
{
    const int node = blockIdx.x * 4 + (threadIdx.x >> 6);
    const int lane = threadIdx.x & 63;
    float2 v = *reinterpret_cast<float2*>(out + (size_t)node * D_OUT + lane * 2);
    v.x = fmaxf(v.x, 0.f);
    v.y = fmaxf(v.y, 0.f);
    float s = v.x + v.y;
    float ss = v.x * v.x + v.y * v.y;
    #pragma unroll
    for (int m = 1; m < 64; m <<= 1) {
        s  += __shfl_xor(s, m, 64);
        ss += __shfl_xor(ss, m, 64);
    }
    float mu = s * (1.f / 128.f);
    float var = ss * (1.f / 128.f) - mu * mu;
    float rs = rsqrtf(var + LN_EPS);
    const float2 gm = *reinterpret_cast<const float2*>(gamma + lane * 2);
    const float2 bt = *reinterpret_cast<const float2*>(beta + lane * 2);
    float2 o;
    o.x = (v.x - mu) * rs * gm.x + bt.x;
    o.y = (v.y - mu) * rs * gm.y + bt.y;
    *reinterpret_cast<float2*>(out + (size_t)node * D_OUT + lane * 2) = o;
}

extern "C" void kernel_launch(void* const* d_in, const int* in_sizes, int n_in,
                              void* d_out, int out_size, void* d_ws, size_t ws_size,
                              hipStream_t stream) {
    const float* x     = (const float*)d_in[0];
    const int*   ei    = (const int*)d_in[1];
    const int*   attr  = (const int*)d_in[2];
    const float* w1    = (const float*)d_in[3];
    const float* b1    = (const float*)d_in[4];
    const float* w2    = (const float*)d_in[5];
    const float* b2    = (const float*)d_in[6];
    const float* sw    = (const float*)d_in[7];
    const float* sb    = (const float*)d_in[8];
    const float* gamma = (const float*)d_in[9];
    const float* beta  = (const float*)d_in[10];
    float* out = (float*)d_out;

    if (ws_size < WS_TOTAL) return;   // fail visibly rather than corrupt (round-2 proved >=225MB)

    char* ws = (char*)d_ws;
    int* cnt    = (int*)(ws + OFF_CNT);
    int* ptr    = (int*)(ws + OFF_PTR);
    int* cursor = (int*)(ws + OFF_CUR);
    int* bsum   = (int*)(ws + OFF_BSUM);
    int* boff   = (int*)(ws + OFF_BOFF);
    int* srows  = (int*)(ws + OFF_SROWS);
    unsigned short* xb    = (unsigned short*)(ws + OFF_XB);
    unsigned short* wcatT = (unsigned short*)(ws + OFF_WCAT);
    float*          bias  = (float*)(ws + OFF_BIAS);
    unsigned short* w2T   = (unsigned short*)(ws + OFF_W2T);
    unsigned short* xabc  = (unsigned short*)(ws + OFF_XABC);
    unsigned short* S     = (unsigned short*)(ws + OFF_S);

    hipMemsetAsync(cnt, 0, (size_t)N_BUCKETS * 4, stream);

    k_cvt_x<<<(N_NODES * D_IN / 4 + 255) / 256, 256, 0, stream>>>(x, xb);
    k_prep_wcat<<<(NJT * 4 * 128 * 32 + 255) / 256, 256, 0, stream>>>(w1, sw, wcatT);
    k_prep_bias<<<(NJT * 128 + 255) / 256, 256, 0, stream>>>(b1, sb, bias);
    k_prep_w2<<<(N_TYPES * 4 * 128 * 32 + 255) / 256, 256, 0, stream>>>(w2, w2T);

    k_hist2<<<(N_EDGES + 255) / 256, 256, 0, stream>>>(ei, attr, cnt);
    k_scanA<<<NSB, 256, 0, stream>>>(cnt, bsum);
    k_scanB<<<1, 256, 0, stream>>>(bsum, boff, ptr);
    k_scanC<<<NSB, 256, 0, stream>>>(cnt, boff, ptr, cursor);
    k_scatter2<<<(N_EDGES + 255) / 256, 256, 0, stream>>>(ei, attr, cursor, srows);

    k_gemm1<<<dim3((N_NODES + 127) / 128, NJT), 256, 0, stream>>>(xb, wcatT, bias, xabc);
    k_bucket<<<(N_BUCKETS + 3) / 4, 256, 0, stream>>>(xabc, ptr, srows, S);
    k_gemm2<<<(N_NODES + 127) / 128, 256, 0, stream>>>(S, w2T, b2, xabc, ptr, out);
    k_ln<<<N_NODES / 4, 256, 0, stream>>>(out, gamma, beta);
}

// Round 5
// 244.516 us; speedup vs baseline: 2.9630x; 1.1896x over previous
//
#include <hip/hip_runtime.h>

#define N_NODES 50000
#define N_EDGES 800000
#define D_IN 128
#define D_OUT 128
#define N_TYPES 4
#define LN_EPS 1e-5f
#define N_BUCKETS (N_TYPES * N_NODES)   // 200000
#define NJT 9                            // 8 w1 halves + 1 self
#define SB_ITEMS 1024
#define NSB ((N_BUCKETS + SB_ITEMS - 1) / SB_ITEMS)   // 196

typedef __attribute__((ext_vector_type(4))) float f32x4;
typedef __attribute__((ext_vector_type(8))) __bf16 bf16x8;
typedef __attribute__((ext_vector_type(8))) unsigned short u16x8;

// ---- workspace layout (bytes), 256-aligned sections ----
constexpr size_t wsal(size_t x) { return (x + 255) & ~size_t(255); }
constexpr size_t OFF_CNT   = 0;                                              // 200000*4
constexpr size_t OFF_PTR   = OFF_CNT  + wsal((size_t)N_BUCKETS * 4);         // 200001*4
constexpr size_t OFF_CUR   = OFF_PTR  + wsal((size_t)(N_BUCKETS + 1) * 4);
constexpr size_t OFF_BSUM  = OFF_CUR  + wsal((size_t)N_BUCKETS * 4);         // 256*4
constexpr size_t OFF_BOFF  = OFF_BSUM + wsal((size_t)256 * 4);
constexpr size_t OFF_SROWS = OFF_BOFF + wsal((size_t)256 * 4);               // 800000*4
constexpr size_t OFF_XB    = OFF_SROWS + wsal((size_t)N_EDGES * 4);          // 12.8MB
constexpr size_t OFF_WCAT  = OFF_XB   + wsal((size_t)N_NODES * D_IN * 2);    // 9*4*128*32*2
constexpr size_t OFF_BIAS  = OFF_WCAT + wsal((size_t)NJT * 4 * 128 * 32 * 2);
constexpr size_t OFF_W2T   = OFF_BIAS + wsal((size_t)NJT * 128 * 4);
constexpr size_t OFF_XABC  = OFF_W2T  + wsal((size_t)N_TYPES * 4 * 128 * 32 * 2);
constexpr size_t OFF_S     = OFF_XABC + wsal((size_t)N_NODES * NJT * 128 * 2);  // 115.2MB
constexpr size_t WS_TOTAL  = OFF_S    + wsal((size_t)N_BUCKETS * 128 * 2);      // +51.2MB ≈ 185MB

__device__ __forceinline__ unsigned short f2bf(float f) {
    unsigned int u = __builtin_bit_cast(unsigned int, f);
    u += 0x7FFFu + ((u >> 16) & 1u);   // RNE; inputs finite
    return (unsigned short)(u >> 16);
}
__device__ __forceinline__ float bf2f_lo(unsigned int u) { return __builtin_bit_cast(float, u << 16); }
__device__ __forceinline__ float bf2f_hi(unsigned int u) { return __builtin_bit_cast(float, u & 0xFFFF0000u); }

// ---------------- prep kernels ----------------
__global__ void k_cvt_x(const float* __restrict__ x, unsigned short* __restrict__ xb) {
    int i = blockIdx.x * blockDim.x + threadIdx.x;
    if (i * 4 >= N_NODES * D_IN) return;
    const float4 v = reinterpret_cast<const float4*>(x)[i];
    ushort4 o;
    o.x = f2bf(v.x); o.y = f2bf(v.y); o.z = f2bf(v.z); o.w = f2bf(v.w);
    reinterpret_cast<ushort4*>(xb)[i] = o;
}

// merged weight prep:
//  seg0: wcatT[jt][ks][jm][kk] = Wcat[ks*32+kk][jt*128+jm]  (147456)
//  seg1: bias[jt][jm]                                        (1152)
//  seg2: w2T[t][ks][f][kk] = w2[t][ks*32+kk][f]              (65536)
#define PREP_N0 (NJT * 4 * 128 * 32)
#define PREP_N1 (NJT * 128)
#define PREP_N2 (N_TYPES * 4 * 128 * 32)
__global__ void k_prep_w(const float* __restrict__ w1, const float* __restrict__ sw,
                         const float* __restrict__ b1, const float* __restrict__ sb,
                         const float* __restrict__ w2,
                         unsigned short* __restrict__ wcatT, float* __restrict__ bias,
                         unsigned short* __restrict__ w2T) {
    int gid = blockIdx.x * blockDim.x + threadIdx.x;
    if (gid < PREP_N0) {
        int kk = gid & 31;
        int jm = (gid >> 5) & 127;
        int ks = (gid >> 12) & 3;
        int jt = gid >> 14;
        int k  = ks * 32 + kk;
        float v;
        if (jt < 8) {
            int t = jt >> 1, half = jt & 1;
            v = w1[((size_t)t * 256 + half * 128 + k) * 128 + jm];
        } else {
            v = sw[(size_t)k * 128 + jm];
        }
        wcatT[gid] = f2bf(v);
        return;
    }
    gid -= PREP_N0;
    if (gid < PREP_N1) {
        int jt = gid >> 7, jm = gid & 127;
        float v = 0.f;
        if (jt < 8) { if (jt & 1) v = b1[(jt >> 1) * 128 + jm]; }
        else v = sb[jm];
        bias[gid] = v;
        return;
    }
    gid -= PREP_N1;
    if (gid < PREP_N2) {
        int kk = gid & 31;
        int f  = (gid >> 5) & 127;
        int ks = (gid >> 12) & 3;
        int t  = gid >> 14;
        float v = w2[((size_t)t * 128 + ks * 32 + kk) * 128 + f];
        w2T[gid] = f2bf(v);
    }
}

// ---------------- (type, col) counting sort ----------------
__global__ void k_hist2(const int* __restrict__ ei, const int* __restrict__ attr,
                        int* __restrict__ cnt) {
    int e = blockIdx.x * blockDim.x + threadIdx.x;
    if (e >= N_EDGES) return;
    int t = attr[e];
    int c = ei[N_EDGES + e];
    atomicAdd(&cnt[t * N_NODES + c], 1);
}

// ---- 3-phase device-wide exclusive scan over cnt[200000] ----
__global__ __launch_bounds__(256) void k_scanA(const int* __restrict__ cnt, int* __restrict__ bsum) {
    __shared__ int red[256];
    const int b = blockIdx.x, tid = threadIdx.x;
    const int base = b * SB_ITEMS + tid * 4;
    int s = 0;
    if (base + 3 < N_BUCKETS) {
        const int4 v = *reinterpret_cast<const int4*>(cnt + base);
        s = v.x + v.y + v.z + v.w;
    } else {
        #pragma unroll
        for (int i = 0; i < 4; ++i) if (base + i < N_BUCKETS) s += cnt[base + i];
    }
    red[tid] = s;
    __syncthreads();
    #pragma unroll
    for (int d = 128; d > 0; d >>= 1) {
        if (tid < d) red[tid] += red[tid + d];
        __syncthreads();
    }
    if (tid == 0) bsum[b] = red[0];
}

__global__ __launch_bounds__(256) void k_scanB(const int* __restrict__ bsum,
                                               int* __restrict__ boff,
                                               int* __restrict__ ptr) {
    __shared__ int sc[256];
    const int tid = threadIdx.x;
    int v = (tid < NSB) ? bsum[tid] : 0;
    sc[tid] = v;
    __syncthreads();
    #pragma unroll
    for (int d = 1; d < 256; d <<= 1) {
        int add = (tid >= d) ? sc[tid - d] : 0;
        __syncthreads();
        sc[tid] += add;
        __syncthreads();
    }
    if (tid < NSB) boff[tid] = sc[tid] - v;   // exclusive
    if (tid == 0) ptr[N_BUCKETS] = N_EDGES;   // total is a known constant
}

__global__ __launch_bounds__(256) void k_scanC(const int* __restrict__ cnt,
                                               const int* __restrict__ boff,
                                               int* __restrict__ ptr,
                                               int* __restrict__ cursor) {
    __shared__ int sc[256];
    const int b = blockIdx.x, tid = threadIdx.x;
    const int base = b * SB_ITEMS + tid * 4;
    int v[4] = {0, 0, 0, 0};
    if (base + 3 < N_BUCKETS) {
        const int4 t4 = *reinterpret_cast<const int4*>(cnt + base);
        v[0] = t4.x; v[1] = t4.y; v[2] = t4.z; v[3] = t4.w;
    } else {
        #pragma unroll
        for (int i = 0; i < 4; ++i) if (base + i < N_BUCKETS) v[i] = cnt[base + i];
    }
    const int s = v[0] + v[1] + v[2] + v[3];
    sc[tid] = s;
    __syncthreads();
    #pragma unroll
    for (int d = 1; d < 256; d <<= 1) {
        int add = (tid >= d) ? sc[tid - d] : 0;
        __syncthreads();
        sc[tid] += add;
        __syncthreads();
    }
    int run = boff[b] + sc[tid] - s;
    #pragma unroll
    for (int i = 0; i < 4; ++i) {
        if (base + i < N_BUCKETS) {
            ptr[base + i] = run;
            cursor[base + i] = run;
            run += v[i];
        }
    }
}

// srows[pos] = source-row of the edge, grouped by (type, col)
__global__ void k_scatter2(const int* __restrict__ ei, const int* __restrict__ attr,
                           int* __restrict__ cursor, int* __restrict__ srows) {
    int e = blockIdx.x * blockDim.x + threadIdx.x;
    if (e >= N_EDGES) return;
    int t = attr[e];
    int c = ei[N_EDGES + e];
    int pos = atomicAdd(&cursor[t * N_NODES + c], 1);
    srows[pos] = ei[e];
}

// ---------------- GEMM1: XABC[n][j] = xb[n] @ Wcat[:,j] + bias[j]  (bf16 out, 50000 x 1152) ----------------
__global__ __launch_bounds__(256, 2) void k_gemm1(
    const unsigned short* __restrict__ xb,
    const unsigned short* __restrict__ wcatT,
    const float* __restrict__ bias,
    unsigned short* __restrict__ xabc)
{
    const int nb = blockIdx.x * 128;
    const int jt = blockIdx.y;

    __shared__ __align__(16) unsigned short sX[128 * 136];  // x rows [n][k], pad 136; reused as out tile [n][j]
    __shared__ __align__(16) unsigned short sW[128 * 32];   // WcatT chunk [j][kk]

    const int tid = threadIdx.x;
    const int lane = tid & 63;
    const int w = tid >> 6;
    const int g = lane >> 4;
    const int c = lane & 15;
    const int wf = w >> 1;   // j half
    const int we = w & 1;    // n half

    // stage x rows (coalesced; clamp OOB rows)
    #pragma unroll
    for (int it = 0; it < 8; ++it) {
        int row = 16 * it + (tid >> 4);
        int node = min(nb + row, N_NODES - 1);
        const u16x8 v = *reinterpret_cast<const u16x8*>(xb + (size_t)node * D_IN + (tid & 15) * 8);
        *reinterpret_cast<u16x8*>(&sX[row * 136 + (tid & 15) * 8]) = v;
    }

    f32x4 acc[4][4];
    #pragma unroll
    for (int ft = 0; ft < 4; ++ft)
        #pragma unroll
        for (int et = 0; et < 4; ++et)
            acc[ft][et] = f32x4{0.f, 0.f, 0.f, 0.f};

    for (int ks = 0; ks < 4; ++ks) {
        __syncthreads();   // covers x staging (ks=0) and prior reads
        {
            const u16x8* gsrc = reinterpret_cast<const u16x8*>(wcatT + (size_t)(jt * 4 + ks) * 4096);
            u16x8* ldst = reinterpret_cast<u16x8*>(sW);
            ldst[tid] = gsrc[tid];
            ldst[tid + 256] = gsrc[tid + 256];
        }
        __syncthreads();
        bf16x8 af[4], bfr[4];
        #pragma unroll
        for (int ft = 0; ft < 4; ++ft)
            af[ft] = *reinterpret_cast<const bf16x8*>(&sW[(64 * wf + 16 * ft + c) * 32 + 8 * g]);
        #pragma unroll
        for (int et = 0; et < 4; ++et)
            bfr[et] = *reinterpret_cast<const bf16x8*>(&sX[(64 * we + 16 * et + c) * 136 + ks * 32 + 8 * g]);
        #pragma unroll
        for (int ft = 0; ft < 4; ++ft)
            #pragma unroll
            for (int et = 0; et < 4; ++et)
                acc[ft][et] = __builtin_amdgcn_mfma_f32_16x16x32_bf16(af[ft], bfr[et], acc[ft][et], 0, 0, 0);
    }
    __syncthreads();   // sX reads done; reuse as output tile

    // + bias, pack bf16 -> sX as [n][j] (u32 pairs)
    {
        float bv[4][4];
        #pragma unroll
        for (int ft = 0; ft < 4; ++ft)
            #pragma unroll
            for (int r = 0; r < 4; ++r)
                bv[ft][r] = bias[jt * 128 + 64 * wf + 16 * ft + 4 * g + r];
        unsigned int* so = reinterpret_cast<unsigned int*>(sX);
        #pragma unroll
        for (int ft = 0; ft < 4; ++ft) {
            #pragma unroll
            for (int et = 0; et < 4; ++et) {
                int n = 64 * we + 16 * et + c;
                int jb = 32 * wf + 8 * ft + 2 * g;   // u32 index within row
                float v0 = acc[ft][et][0] + bv[ft][0];
                float v1 = acc[ft][et][1] + bv[ft][1];
                float v2 = acc[ft][et][2] + bv[ft][2];
                float v3 = acc[ft][et][3] + bv[ft][3];
                so[n * 68 + jb + 0] = (unsigned int)f2bf(v0) | ((unsigned int)f2bf(v1) << 16);
                so[n * 68 + jb + 1] = (unsigned int)f2bf(v2) | ((unsigned int)f2bf(v3) << 16);
            }
        }
    }
    __syncthreads();

    // coalesced write to XABC
    #pragma unroll
    for (int it = 0; it < 8; ++it) {
        int row = 16 * it + (tid >> 4);
        int node = nb + row;
        if (node < N_NODES) {
            const u16x8 v = *reinterpret_cast<const u16x8*>(&sX[row * 136 + (tid & 15) * 8]);
            *reinterpret_cast<u16x8*>(xabc + (size_t)node * (NJT * 128) + jt * 128 + (tid & 15) * 8) = v;
        }
    }
}

// ---------------- bucket aggregation: S[t*N+n] = sum_{e in (t,n)} relu(XA_t[row_e] + XB_t[n]) ----------------
// 4-wide unrolled independent gathers to raise outstanding-request count (latency-bound kernel).
__global__ __launch_bounds__(256) void k_bucket(const unsigned short* __restrict__ xabc,
                                                const int* __restrict__ ptr,
                                                const int* __restrict__ srows,
                                                unsigned short* __restrict__ S)
{
    const int b = blockIdx.x * 4 + (threadIdx.x >> 6);
    if (b >= N_BUCKETS) return;
    const int lane = threadIdx.x & 63;
    const int t = b / N_NODES;
    const int n = b - t * N_NODES;
    const int s = ptr[b], e = ptr[b + 1];
    const unsigned int* x32 = reinterpret_cast<const unsigned int*>(xabc);
    const unsigned int aoff = 2 * t * 64 + lane;
    float a0 = 0.f, a1 = 0.f;
    if (s < e) {
        const unsigned int xbv = x32[(size_t)n * 576 + (2 * t + 1) * 64 + lane];  // XB_t[n] (+b1 baked)
        const float xb0 = bf2f_lo(xbv), xb1 = bf2f_hi(xbv);
        int j = s;
        for (; j + 3 < e; j += 4) {
            int r0 = srows[j], r1 = srows[j + 1], r2 = srows[j + 2], r3 = srows[j + 3];
            unsigned int v0 = x32[(size_t)r0 * 576 + aoff];
            unsigned int v1 = x32[(size_t)r1 * 576 + aoff];
            unsigned int v2 = x32[(size_t)r2 * 576 + aoff];
            unsigned int v3 = x32[(size_t)r3 * 576 + aoff];
            a0 += fmaxf(bf2f_lo(v0) + xb0, 0.f) + fmaxf(bf2f_lo(v1) + xb0, 0.f)
                + fmaxf(bf2f_lo(v2) + xb0, 0.f) + fmaxf(bf2f_lo(v3) + xb0, 0.f);
            a1 += fmaxf(bf2f_hi(v0) + xb1, 0.f) + fmaxf(bf2f_hi(v1) + xb1, 0.f)
                + fmaxf(bf2f_hi(v2) + xb1, 0.f) + fmaxf(bf2f_hi(v3) + xb1, 0.f);
        }
        int left = e - j;
        if (left & 2) {
            int r0 = srows[j], r1 = srows[j + 1];
            unsigned int v0 = x32[(size_t)r0 * 576 + aoff];
            unsigned int v1 = x32[(size_t)r1 * 576 + aoff];
            a0 += fmaxf(bf2f_lo(v0) + xb0, 0.f) + fmaxf(bf2f_lo(v1) + xb0, 0.f);
            a1 += fmaxf(bf2f_hi(v0) + xb1, 0.f) + fmaxf(bf2f_hi(v1) + xb1, 0.f);
            j += 2;
        }
        if (left & 1) {
            unsigned int v0 = x32[(size_t)srows[j] * 576 + aoff];
            a0 += fmaxf(bf2f_lo(v0) + xb0, 0.f);
            a1 += fmaxf(bf2f_hi(v0) + xb1, 0.f);
        }
    }
    reinterpret_cast<unsigned int*>(S)[(size_t)b * 64 + lane] =
        (unsigned int)f2bf(a0) | ((unsigned int)f2bf(a1) << 16);
}

// ---------------- GEMM2 + ReLU + LayerNorm fused ----------------
// out[n] = LN(relu(XC[n] + sum_t S_t[n] @ W2_t + sum_t cnt_{t,n} * b2_t))
__global__ __launch_bounds__(256, 2) void k_gemm2_ln(
    const unsigned short* __restrict__ S,
    const unsigned short* __restrict__ w2T,
    const float* __restrict__ b2,
    const unsigned short* __restrict__ xabc,
    const int* __restrict__ ptr,
    const float* __restrict__ gamma,
    const float* __restrict__ beta,
    float* __restrict__ out)
{
    const int nb = blockIdx.x * 128;
    // manual shared layout so the fp32 row buffer can alias sS+sW2 after MFMA
    __shared__ __align__(16) unsigned char sm[128 * 136 * 2 + 4 * 128 * 32 * 2 + 512 * 4];
    unsigned short* sS  = reinterpret_cast<unsigned short*>(sm);               // [128*136]
    unsigned short* sW2 = reinterpret_cast<unsigned short*>(sm + 34816);       // [4*128*32]
    float* sB2          = reinterpret_cast<float*>(sm + 34816 + 32768);        // [512]
    float* rows         = reinterpret_cast<float*>(sm);                        // [128][132] alias, used post-MFMA

    const int tid = threadIdx.x;
    const int lane = tid & 63;
    const int w = tid >> 6;
    const int g = lane >> 4;
    const int c = lane & 15;
    const int wf = w >> 1;   // f half
    const int we = w & 1;    // n half

    sB2[tid] = b2[tid];
    sB2[tid + 256] = b2[tid + 256];

    f32x4 acc[4][4];
    #pragma unroll
    for (int ft = 0; ft < 4; ++ft)
        #pragma unroll
        for (int et = 0; et < 4; ++et)
            acc[ft][et] = f32x4{0.f, 0.f, 0.f, 0.f};

    for (int t = 0; t < N_TYPES; ++t) {
        __syncthreads();   // prev reads done before restage
        // stage S tile (coalesced, clamp)
        #pragma unroll
        for (int it = 0; it < 8; ++it) {
            int row = 16 * it + (tid >> 4);
            int bidx = t * N_NODES + min(nb + row, N_NODES - 1);
            const u16x8 v = *reinterpret_cast<const u16x8*>(S + (size_t)bidx * 128 + (tid & 15) * 8);
            *reinterpret_cast<u16x8*>(&sS[row * 136 + (tid & 15) * 8]) = v;
        }
        // stage full W2T[t] (linear copy)
        {
            const u16x8* gsrc = reinterpret_cast<const u16x8*>(w2T + (size_t)t * 16384);
            u16x8* ldst = reinterpret_cast<u16x8*>(sW2);
            #pragma unroll
            for (int it = 0; it < 8; ++it)
                ldst[tid + 256 * it] = gsrc[tid + 256 * it];
        }
        __syncthreads();
        #pragma unroll
        for (int ks = 0; ks < 4; ++ks) {
            bf16x8 af[4], bfr[4];
            #pragma unroll
            for (int ft = 0; ft < 4; ++ft)
                af[ft] = *reinterpret_cast<const bf16x8*>(&sW2[ks * 4096 + (64 * wf + 16 * ft + c) * 32 + 8 * g]);
            #pragma unroll
            for (int et = 0; et < 4; ++et)
                bfr[et] = *reinterpret_cast<const bf16x8*>(&sS[(64 * we + 16 * et + c) * 136 + ks * 32 + 8 * g]);
            #pragma unroll
            for (int ft = 0; ft < 4; ++ft)
                #pragma unroll
                for (int et = 0; et < 4; ++et)
                    acc[ft][et] = __builtin_amdgcn_mfma_f32_16x16x32_bf16(af[ft], bfr[et], acc[ft][et], 0, 0, 0);
        }
    }
    __syncthreads();   // MFMA reads of sS/sW2 done; rows[] may now overwrite them

    // epilogue: + XC + cnt*b2 -> rows[n][f] (fp32, stride 132)
    const unsigned int* x32 = reinterpret_cast<const unsigned int*>(xabc);
    #pragma unroll
    for (int et = 0; et < 4; ++et) {
        int n = 64 * we + 16 * et + c;
        int node = nb + n;
        if (node >= N_NODES) continue;
        float cnt4[N_TYPES];
        #pragma unroll
        for (int t = 0; t < N_TYPES; ++t)
            cnt4[t] = (float)(ptr[t * N_NODES + node + 1] - ptr[t * N_NODES + node]);
        #pragma unroll
        for (int ft = 0; ft < 4; ++ft) {
            int f0 = 64 * wf + 16 * ft + 4 * g;
            unsigned int xc0 = x32[(size_t)node * 576 + 512 + (f0 >> 1)];
            unsigned int xc1 = x32[(size_t)node * 576 + 512 + (f0 >> 1) + 1];
            float v[4];
            v[0] = acc[ft][et][0] + bf2f_lo(xc0);
            v[1] = acc[ft][et][1] + bf2f_hi(xc0);
            v[2] = acc[ft][et][2] + bf2f_lo(xc1);
            v[3] = acc[ft][et][3] + bf2f_hi(xc1);
            #pragma unroll
            for (int r = 0; r < 4; ++r) {
                float bs = 0.f;
                #pragma unroll
                for (int t = 0; t < N_TYPES; ++t)
                    bs = fmaf(cnt4[t], sB2[t * 128 + f0 + r], bs);
                v[r] += bs;
            }
            *reinterpret_cast<float4*>(&rows[n * 132 + f0]) = *reinterpret_cast<float4*>(v);
        }
    }
    __syncthreads();

    // ReLU + LN: each wave handles 32 rows
    for (int rr = 0; rr < 32; ++rr) {
        int r = w * 32 + rr;
        int node = nb + r;
        if (node >= N_NODES) break;
        float2 v = *reinterpret_cast<float2*>(&rows[r * 132 + lane * 2]);
        v.x = fmaxf(v.x, 0.f);
        v.y = fmaxf(v.y, 0.f);
        float s = v.x + v.y;
        float ss = v.x * v.x + v.y * v.y;
        #pragma unroll
        for (int m = 1; m < 64; m <<= 1) {
            s  += __shfl_xor(s, m, 64);
            ss += __shfl_xor(ss, m, 64);
        }
        float mu = s * (1.f / 128.f);
        float var = ss * (1.f / 128.f) - mu * mu;
        float rs = rsqrtf(var + LN_EPS);
        const float2 gm = *reinterpret_cast<const float2*>(gamma + lane * 2);
        const float2 bt = *reinterpret_cast<const float2*>(beta + lane * 2);
        float2 o;
        o.x = (v.x - mu) * rs * gm.x + bt.x;
        o.y = (v.y - mu) * rs * gm.y + bt.y;
        *reinterpret_cast<float2*>(out + (size_t)node * D_OUT + lane * 2) = o;
    }
}

extern "C" void kernel_launch(void* const* d_in, const int* in_sizes, int n_in,
                              void* d_out, int out_size, void* d_ws, size_t ws_size,
                              hipStream_t stream) {
    const float* x     = (const float*)d_in[0];
    const int*   ei    = (const int*)d_in[1];
    const int*   attr  = (const int*)d_in[2];
    const float* w1    = (const float*)d_in[3];
    const float* b1    = (const float*)d_in[4];
    const float* w2    = (const float*)d_in[5];
    const float* b2    = (const float*)d_in[6];
    const float* sw    = (const float*)d_in[7];
    const float* sb    = (const float*)d_in[8];
    const float* gamma = (const float*)d_in[9];
    const float* beta  = (const float*)d_in[10];
    float* out = (float*)d_out;

    if (ws_size < WS_TOTAL) return;   // fail visibly rather than corrupt

    char* ws = (char*)d_ws;
    int* cnt    = (int*)(ws + OFF_CNT);
    int* ptr    = (int*)(ws + OFF_PTR);
    int* cursor = (int*)(ws + OFF_CUR);
    int* bsum   = (int*)(ws + OFF_BSUM);
    int* boff   = (int*)(ws + OFF_BOFF);
    int* srows  = (int*)(ws + OFF_SROWS);
    unsigned short* xb    = (unsigned short*)(ws + OFF_XB);
    unsigned short* wcatT = (unsigned short*)(ws + OFF_WCAT);
    float*          bias  = (float*)(ws + OFF_BIAS);
    unsigned short* w2T   = (unsigned short*)(ws + OFF_W2T);
    unsigned short* xabc  = (unsigned short*)(ws + OFF_XABC);
    unsigned short* S     = (unsigned short*)(ws + OFF_S);

    hipMemsetAsync(cnt, 0, (size_t)N_BUCKETS * 4, stream);

    k_cvt_x<<<(N_NODES * D_IN / 4 + 255) / 256, 256, 0, stream>>>(x, xb);
    k_prep_w<<<(PREP_N0 + PREP_N1 + PREP_N2 + 255) / 256, 256, 0, stream>>>(
        w1, sw, b1, sb, w2, wcatT, bias, w2T);

    k_hist2<<<(N_EDGES + 255) / 256, 256, 0, stream>>>(ei, attr, cnt);
    k_scanA<<<NSB, 256, 0, stream>>>(cnt, bsum);
    k_scanB<<<1, 256, 0, stream>>>(bsum, boff, ptr);
    k_scanC<<<NSB, 256, 0, stream>>>(cnt, boff, ptr, cursor);
    k_scatter2<<<(N_EDGES + 255) / 256, 256, 0, stream>>>(ei, attr, cursor, srows);

    k_gemm1<<<dim3((N_NODES + 127) / 128, NJT), 256, 0, stream>>>(xb, wcatT, bias, xabc);
    k_bucket<<<(N_BUCKETS + 3) / 4, 256, 0, stream>>>(xabc, ptr, srows, S);
    k_gemm2_ln<<<(N_NODES + 127) / 128, 256, 0, stream>>>(S, w2T, b2, xabc, ptr, gamma, beta, out);
}

// Round 6
// 234.400 us; speedup vs baseline: 3.0909x; 1.0432x over previous
//
#include <hip/hip_runtime.h>

#define N_NODES 50000
#define N_EDGES 800000
#define D_IN 128
#define D_OUT 128
#define N_TYPES 4
#define LN_EPS 1e-5f
#define N_BUCKETS (N_TYPES * N_NODES)   // 200000
#define NJT 9                            // 8 w1 halves + 1 self
#define SB_ITEMS 1024
#define NSB ((N_BUCKETS + SB_ITEMS - 1) / SB_ITEMS)   // 196

typedef __attribute__((ext_vector_type(4))) float f32x4;
typedef __attribute__((ext_vector_type(8))) __bf16 bf16x8;
typedef __attribute__((ext_vector_type(8))) unsigned short u16x8;

// ---- workspace layout (bytes), 256-aligned sections ----
constexpr size_t wsal(size_t x) { return (x + 255) & ~size_t(255); }
constexpr size_t OFF_CNT   = 0;                                              // 200000*4
constexpr size_t OFF_PTR   = OFF_CNT  + wsal((size_t)N_BUCKETS * 4);         // 200001*4
constexpr size_t OFF_CUR   = OFF_PTR  + wsal((size_t)(N_BUCKETS + 1) * 4);
constexpr size_t OFF_BSUM  = OFF_CUR  + wsal((size_t)N_BUCKETS * 4);         // 256*4
constexpr size_t OFF_BOFF  = OFF_BSUM + wsal((size_t)256 * 4);
constexpr size_t OFF_SROWS = OFF_BOFF + wsal((size_t)256 * 4);               // 800000*4
constexpr size_t OFF_XB    = OFF_SROWS + wsal((size_t)N_EDGES * 4);          // 12.8MB
constexpr size_t OFF_WCAT  = OFF_XB   + wsal((size_t)N_NODES * D_IN * 2);    // 9*4*128*32*2
constexpr size_t OFF_BIAS  = OFF_WCAT + wsal((size_t)NJT * 4 * 128 * 32 * 2);
constexpr size_t OFF_W2T   = OFF_BIAS + wsal((size_t)NJT * 128 * 4);
constexpr size_t OFF_XABC  = OFF_W2T  + wsal((size_t)N_TYPES * 4 * 128 * 32 * 2);
constexpr size_t OFF_S     = OFF_XABC + wsal((size_t)N_NODES * NJT * 128 * 2);  // 115.2MB
constexpr size_t WS_TOTAL  = OFF_S    + wsal((size_t)N_BUCKETS * 128 * 2);      // +51.2MB ≈ 185MB

__device__ __forceinline__ unsigned short f2bf(float f) {
    unsigned int u = __builtin_bit_cast(unsigned int, f);
    u += 0x7FFFu + ((u >> 16) & 1u);   // RNE; inputs finite
    return (unsigned short)(u >> 16);
}
__device__ __forceinline__ float bf2f_lo(unsigned int u) { return __builtin_bit_cast(float, u << 16); }
__device__ __forceinline__ float bf2f_hi(unsigned int u) { return __builtin_bit_cast(float, u & 0xFFFF0000u); }

// ---------------- merged prep: x->bf16 | weight transposes | (type,col) histogram ----------------
#define PREP_N0 (NJT * 4 * 128 * 32)
#define PREP_N1 (NJT * 128)
#define PREP_N2 (N_TYPES * 4 * 128 * 32)
#define NB_CVT  (N_NODES * D_IN / 4 / 256)                       // 6250 (exact)
#define NB_PREP ((PREP_N0 + PREP_N1 + PREP_N2 + 255) / 256)      // 837
#define NB_HIST ((N_EDGES + 255) / 256)                          // 3125

__global__ __launch_bounds__(256) void k_prep_all(
    const float* __restrict__ x,
    const float* __restrict__ w1, const float* __restrict__ sw,
    const float* __restrict__ b1, const float* __restrict__ sb,
    const float* __restrict__ w2,
    const int* __restrict__ ei, const int* __restrict__ attr,
    unsigned short* __restrict__ xb,
    unsigned short* __restrict__ wcatT, float* __restrict__ bias,
    unsigned short* __restrict__ w2T,
    int* __restrict__ cnt)
{
    const int bx = blockIdx.x;
    const int tid = threadIdx.x;
    if (bx < NB_CVT) {
        int i = bx * 256 + tid;
        const float4 v = reinterpret_cast<const float4*>(x)[i];
        ushort4 o;
        o.x = f2bf(v.x); o.y = f2bf(v.y); o.z = f2bf(v.z); o.w = f2bf(v.w);
        reinterpret_cast<ushort4*>(xb)[i] = o;
        return;
    }
    if (bx < NB_CVT + NB_PREP) {
        int gid = (bx - NB_CVT) * 256 + tid;
        if (gid < PREP_N0) {
            // wcatT[jt][ks][jm][kk] = Wcat[ks*32+kk][jt*128+jm]
            int kk = gid & 31;
            int jm = (gid >> 5) & 127;
            int ks = (gid >> 12) & 3;
            int jt = gid >> 14;
            int k  = ks * 32 + kk;
            float v;
            if (jt < 8) {
                int t = jt >> 1, half = jt & 1;
                v = w1[((size_t)t * 256 + half * 128 + k) * 128 + jm];
            } else {
                v = sw[(size_t)k * 128 + jm];
            }
            wcatT[gid] = f2bf(v);
            return;
        }
        gid -= PREP_N0;
        if (gid < PREP_N1) {
            int jt = gid >> 7, jm = gid & 127;
            float v = 0.f;
            if (jt < 8) { if (jt & 1) v = b1[(jt >> 1) * 128 + jm]; }
            else v = sb[jm];
            bias[gid] = v;
            return;
        }
        gid -= PREP_N1;
        if (gid < PREP_N2) {
            // w2T[t][ks][f][kk] = w2[t][ks*32+kk][f]
            int kk = gid & 31;
            int f  = (gid >> 5) & 127;
            int ks = (gid >> 12) & 3;
            int t  = gid >> 14;
            float v = w2[((size_t)t * 128 + ks * 32 + kk) * 128 + f];
            w2T[gid] = f2bf(v);
        }
        return;
    }
    {
        int e = (bx - NB_CVT - NB_PREP) * 256 + tid;
        if (e < N_EDGES) {
            int t = attr[e];
            int c = ei[N_EDGES + e];
            atomicAdd(&cnt[t * N_NODES + c], 1);
        }
    }
}

// ---- 3-phase device-wide exclusive scan over cnt[200000] ----
__global__ __launch_bounds__(256) void k_scanA(const int* __restrict__ cnt, int* __restrict__ bsum) {
    __shared__ int red[256];
    const int b = blockIdx.x, tid = threadIdx.x;
    const int base = b * SB_ITEMS + tid * 4;
    int s = 0;
    if (base + 3 < N_BUCKETS) {
        const int4 v = *reinterpret_cast<const int4*>(cnt + base);
        s = v.x + v.y + v.z + v.w;
    } else {
        #pragma unroll
        for (int i = 0; i < 4; ++i) if (base + i < N_BUCKETS) s += cnt[base + i];
    }
    red[tid] = s;
    __syncthreads();
    #pragma unroll
    for (int d = 128; d > 0; d >>= 1) {
        if (tid < d) red[tid] += red[tid + d];
        __syncthreads();
    }
    if (tid == 0) bsum[b] = red[0];
}

__global__ __launch_bounds__(256) void k_scanB(const int* __restrict__ bsum,
                                               int* __restrict__ boff,
                                               int* __restrict__ ptr) {
    __shared__ int sc[256];
    const int tid = threadIdx.x;
    int v = (tid < NSB) ? bsum[tid] : 0;
    sc[tid] = v;
    __syncthreads();
    #pragma unroll
    for (int d = 1; d < 256; d <<= 1) {
        int add = (tid >= d) ? sc[tid - d] : 0;
        __syncthreads();
        sc[tid] += add;
        __syncthreads();
    }
    if (tid < NSB) boff[tid] = sc[tid] - v;   // exclusive
    if (tid == 0) ptr[N_BUCKETS] = N_EDGES;   // total is a known constant
}

__global__ __launch_bounds__(256) void k_scanC(const int* __restrict__ cnt,
                                               const int* __restrict__ boff,
                                               int* __restrict__ ptr,
                                               int* __restrict__ cursor) {
    __shared__ int sc[256];
    const int b = blockIdx.x, tid = threadIdx.x;
    const int base = b * SB_ITEMS + tid * 4;
    int v[4] = {0, 0, 0, 0};
    if (base + 3 < N_BUCKETS) {
        const int4 t4 = *reinterpret_cast<const int4*>(cnt + base);
        v[0] = t4.x; v[1] = t4.y; v[2] = t4.z; v[3] = t4.w;
    } else {
        #pragma unroll
        for (int i = 0; i < 4; ++i) if (base + i < N_BUCKETS) v[i] = cnt[base + i];
    }
    const int s = v[0] + v[1] + v[2] + v[3];
    sc[tid] = s;
    __syncthreads();
    #pragma unroll
    for (int d = 1; d < 256; d <<= 1) {
        int add = (tid >= d) ? sc[tid - d] : 0;
        __syncthreads();
        sc[tid] += add;
        __syncthreads();
    }
    int run = boff[b] + sc[tid] - s;
    #pragma unroll
    for (int i = 0; i < 4; ++i) {
        if (base + i < N_BUCKETS) {
            ptr[base + i] = run;
            cursor[base + i] = run;
            run += v[i];
        }
    }
}

// srows[pos] = source-row of the edge, grouped by (type, col)
__global__ void k_scatter2(const int* __restrict__ ei, const int* __restrict__ attr,
                           int* __restrict__ cursor, int* __restrict__ srows) {
    int e = blockIdx.x * blockDim.x + threadIdx.x;
    if (e >= N_EDGES) return;
    int t = attr[e];
    int c = ei[N_EDGES + e];
    int pos = atomicAdd(&cursor[t * N_NODES + c], 1);
    srows[pos] = ei[e];
}

// ---------------- GEMM1: XABC[n][j] = xb[n] @ Wcat[:,j] + bias[j]  (bf16 out, 50000 x 1152) ----------------
// full 32KB weight slab staged once -> single barrier pair around a straight 16-MFMA run
__global__ __launch_bounds__(256, 2) void k_gemm1(
    const unsigned short* __restrict__ xb,
    const unsigned short* __restrict__ wcatT,
    const float* __restrict__ bias,
    unsigned short* __restrict__ xabc)
{
    const int nb = blockIdx.x * 128;
    const int jt = blockIdx.y;

    __shared__ __align__(16) unsigned short sX[128 * 136];  // x rows [n][k], pad 136; reused as out tile [n][j]
    __shared__ __align__(16) unsigned short sW[4 * 128 * 32]; // full per-jt weight slab (32KB)

    const int tid = threadIdx.x;
    const int lane = tid & 63;
    const int w = tid >> 6;
    const int g = lane >> 4;
    const int c = lane & 15;
    const int wf = w >> 1;   // j half
    const int we = w & 1;    // n half

    // stage x rows (coalesced; clamp OOB rows)
    #pragma unroll
    for (int it = 0; it < 8; ++it) {
        int row = 16 * it + (tid >> 4);
        int node = min(nb + row, N_NODES - 1);
        const u16x8 v = *reinterpret_cast<const u16x8*>(xb + (size_t)node * D_IN + (tid & 15) * 8);
        *reinterpret_cast<u16x8*>(&sX[row * 136 + (tid & 15) * 8]) = v;
    }
    // stage full weight slab for this jt
    {
        const u16x8* gsrc = reinterpret_cast<const u16x8*>(wcatT + (size_t)jt * 16384);
        u16x8* ldst = reinterpret_cast<u16x8*>(sW);
        #pragma unroll
        for (int it = 0; it < 8; ++it)
            ldst[tid + 256 * it] = gsrc[tid + 256 * it];
    }

    f32x4 acc[4][4];
    #pragma unroll
    for (int ft = 0; ft < 4; ++ft)
        #pragma unroll
        for (int et = 0; et < 4; ++et)
            acc[ft][et] = f32x4{0.f, 0.f, 0.f, 0.f};

    __syncthreads();

    #pragma unroll
    for (int ks = 0; ks < 4; ++ks) {
        bf16x8 af[4], bfr[4];
        #pragma unroll
        for (int ft = 0; ft < 4; ++ft)
            af[ft] = *reinterpret_cast<const bf16x8*>(&sW[ks * 4096 + (64 * wf + 16 * ft + c) * 32 + 8 * g]);
        #pragma unroll
        for (int et = 0; et < 4; ++et)
            bfr[et] = *reinterpret_cast<const bf16x8*>(&sX[(64 * we + 16 * et + c) * 136 + ks * 32 + 8 * g]);
        #pragma unroll
        for (int ft = 0; ft < 4; ++ft)
            #pragma unroll
            for (int et = 0; et < 4; ++et)
                acc[ft][et] = __builtin_amdgcn_mfma_f32_16x16x32_bf16(af[ft], bfr[et], acc[ft][et], 0, 0, 0);
    }
    __syncthreads();   // sX reads done; reuse as output tile

    // + bias, pack bf16 -> sX as [n][j] (u32 pairs)
    {
        float bv[4][4];
        #pragma unroll
        for (int ft = 0; ft < 4; ++ft)
            #pragma unroll
            for (int r = 0; r < 4; ++r)
                bv[ft][r] = bias[jt * 128 + 64 * wf + 16 * ft + 4 * g + r];
        unsigned int* so = reinterpret_cast<unsigned int*>(sX);
        #pragma unroll
        for (int ft = 0; ft < 4; ++ft) {
            #pragma unroll
            for (int et = 0; et < 4; ++et) {
                int n = 64 * we + 16 * et + c;
                int jb = 32 * wf + 8 * ft + 2 * g;   // u32 index within row
                float v0 = acc[ft][et][0] + bv[ft][0];
                float v1 = acc[ft][et][1] + bv[ft][1];
                float v2 = acc[ft][et][2] + bv[ft][2];
                float v3 = acc[ft][et][3] + bv[ft][3];
                so[n * 68 + jb + 0] = (unsigned int)f2bf(v0) | ((unsigned int)f2bf(v1) << 16);
                so[n * 68 + jb + 1] = (unsigned int)f2bf(v2) | ((unsigned int)f2bf(v3) << 16);
            }
        }
    }
    __syncthreads();

    // coalesced write to XABC
    #pragma unroll
    for (int it = 0; it < 8; ++it) {
        int row = 16 * it + (tid >> 4);
        int node = nb + row;
        if (node < N_NODES) {
            const u16x8 v = *reinterpret_cast<const u16x8*>(&sX[row * 136 + (tid & 15) * 8]);
            *reinterpret_cast<u16x8*>(xabc + (size_t)node * (NJT * 128) + jt * 128 + (tid & 15) * 8) = v;
        }
    }
}

// ---------------- bucket aggregation: S[t*N+n] = sum_{e in (t,n)} relu(XA_t[row_e] + XB_t[n]) ----------------
// 8-wide unrolled independent gathers + straight-line 4/2/1 remainder (latency-bound kernel).
__global__ __launch_bounds__(256) void k_bucket(const unsigned short* __restrict__ xabc,
                                                const int* __restrict__ ptr,
                                                const int* __restrict__ srows,
                                                unsigned short* __restrict__ S)
{
    const int b = blockIdx.x * 4 + (threadIdx.x >> 6);
    if (b >= N_BUCKETS) return;
    const int lane = threadIdx.x & 63;
    const int t = b / N_NODES;
    const int n = b - t * N_NODES;
    const int s = ptr[b], e = ptr[b + 1];
    const unsigned int* x32 = reinterpret_cast<const unsigned int*>(xabc);
    const unsigned int aoff = 2 * t * 64 + lane;
    float a0 = 0.f, a1 = 0.f;
    if (s < e) {
        const unsigned int xbv = x32[(size_t)n * 576 + (2 * t + 1) * 64 + lane];  // XB_t[n] (+b1 baked)
        const float xb0 = bf2f_lo(xbv), xb1 = bf2f_hi(xbv);
        int j = s;
        for (; j + 7 < e; j += 8) {
            int r0 = srows[j],     r1 = srows[j + 1], r2 = srows[j + 2], r3 = srows[j + 3];
            int r4 = srows[j + 4], r5 = srows[j + 5], r6 = srows[j + 6], r7 = srows[j + 7];
            unsigned int v0 = x32[(size_t)r0 * 576 + aoff];
            unsigned int v1 = x32[(size_t)r1 * 576 + aoff];
            unsigned int v2 = x32[(size_t)r2 * 576 + aoff];
            unsigned int v3 = x32[(size_t)r3 * 576 + aoff];
            unsigned int v4 = x32[(size_t)r4 * 576 + aoff];
            unsigned int v5 = x32[(size_t)r5 * 576 + aoff];
            unsigned int v6 = x32[(size_t)r6 * 576 + aoff];
            unsigned int v7 = x32[(size_t)r7 * 576 + aoff];
            a0 += fmaxf(bf2f_lo(v0) + xb0, 0.f) + fmaxf(bf2f_lo(v1) + xb0, 0.f)
                + fmaxf(bf2f_lo(v2) + xb0, 0.f) + fmaxf(bf2f_lo(v3) + xb0, 0.f)
                + fmaxf(bf2f_lo(v4) + xb0, 0.f) + fmaxf(bf2f_lo(v5) + xb0, 0.f)
                + fmaxf(bf2f_lo(v6) + xb0, 0.f) + fmaxf(bf2f_lo(v7) + xb0, 0.f);
            a1 += fmaxf(bf2f_hi(v0) + xb1, 0.f) + fmaxf(bf2f_hi(v1) + xb1, 0.f)
                + fmaxf(bf2f_hi(v2) + xb1, 0.f) + fmaxf(bf2f_hi(v3) + xb1, 0.f)
                + fmaxf(bf2f_hi(v4) + xb1, 0.f) + fmaxf(bf2f_hi(v5) + xb1, 0.f)
                + fmaxf(bf2f_hi(v6) + xb1, 0.f) + fmaxf(bf2f_hi(v7) + xb1, 0.f);
        }
        int left = e - j;
        if (left & 4) {
            int r0 = srows[j], r1 = srows[j + 1], r2 = srows[j + 2], r3 = srows[j + 3];
            unsigned int v0 = x32[(size_t)r0 * 576 + aoff];
            unsigned int v1 = x32[(size_t)r1 * 576 + aoff];
            unsigned int v2 = x32[(size_t)r2 * 576 + aoff];
            unsigned int v3 = x32[(size_t)r3 * 576 + aoff];
            a0 += fmaxf(bf2f_lo(v0) + xb0, 0.f) + fmaxf(bf2f_lo(v1) + xb0, 0.f)
                + fmaxf(bf2f_lo(v2) + xb0, 0.f) + fmaxf(bf2f_lo(v3) + xb0, 0.f);
            a1 += fmaxf(bf2f_hi(v0) + xb1, 0.f) + fmaxf(bf2f_hi(v1) + xb1, 0.f)
                + fmaxf(bf2f_hi(v2) + xb1, 0.f) + fmaxf(bf2f_hi(v3) + xb1, 0.f);
            j += 4;
        }
        if (left & 2) {
            int r0 = srows[j], r1 = srows[j + 1];
            unsigned int v0 = x32[(size_t)r0 * 576 + aoff];
            unsigned int v1 = x32[(size_t)r1 * 576 + aoff];
            a0 += fmaxf(bf2f_lo(v0) + xb0, 0.f) + fmaxf(bf2f_lo(v1) + xb0, 0.f);
            a1 += fmaxf(bf2f_hi(v0) + xb1, 0.f) + fmaxf(bf2f_hi(v1) + xb1, 0.f);
            j += 2;
        }
        if (left & 1) {
            unsigned int v0 = x32[(size_t)srows[j] * 576 + aoff];
            a0 += fmaxf(bf2f_lo(v0) + xb0, 0.f);
            a1 += fmaxf(bf2f_hi(v0) + xb1, 0.f);
        }
    }
    reinterpret_cast<unsigned int*>(S)[(size_t)b * 64 + lane] =
        (unsigned int)f2bf(a0) | ((unsigned int)f2bf(a1) << 16);
}

// ---------------- GEMM2 + ReLU + LayerNorm fused ----------------
// out[n] = LN(relu(XC[n] + sum_t S_t[n] @ W2_t + sum_t cnt_{t,n} * b2_t))
__global__ __launch_bounds__(256, 2) void k_gemm2_ln(
    const unsigned short* __restrict__ S,
    const unsigned short* __restrict__ w2T,
    const float* __restrict__ b2,
    const unsigned short* __restrict__ xabc,
    const int* __restrict__ ptr,
    const float* __restrict__ gamma,
    const float* __restrict__ beta,
    float* __restrict__ out)
{
    const int nb = blockIdx.x * 128;
    // manual shared layout so the fp32 row buffer can alias sS+sW2 after MFMA
    __shared__ __align__(16) unsigned char sm[128 * 136 * 2 + 4 * 128 * 32 * 2 + 512 * 4];
    unsigned short* sS  = reinterpret_cast<unsigned short*>(sm);               // [128*136]
    unsigned short* sW2 = reinterpret_cast<unsigned short*>(sm + 34816);       // [4*128*32]
    float* sB2          = reinterpret_cast<float*>(sm + 34816 + 32768);        // [512]
    float* rows         = reinterpret_cast<float*>(sm);                        // [128][132] alias, used post-MFMA

    const int tid = threadIdx.x;
    const int lane = tid & 63;
    const int w = tid >> 6;
    const int g = lane >> 4;
    const int c = lane & 15;
    const int wf = w >> 1;   // f half
    const int we = w & 1;    // n half

    sB2[tid] = b2[tid];
    sB2[tid + 256] = b2[tid + 256];

    f32x4 acc[4][4];
    #pragma unroll
    for (int ft = 0; ft < 4; ++ft)
        #pragma unroll
        for (int et = 0; et < 4; ++et)
            acc[ft][et] = f32x4{0.f, 0.f, 0.f, 0.f};

    for (int t = 0; t < N_TYPES; ++t) {
        __syncthreads();   // prev reads done before restage
        // stage S tile (coalesced, clamp)
        #pragma unroll
        for (int it = 0; it < 8; ++it) {
            int row = 16 * it + (tid >> 4);
            int bidx = t * N_NODES + min(nb + row, N_NODES - 1);
            const u16x8 v = *reinterpret_cast<const u16x8*>(S + (size_t)bidx * 128 + (tid & 15) * 8);
            *reinterpret_cast<u16x8*>(&sS[row * 136 + (tid & 15) * 8]) = v;
        }
        // stage full W2T[t] (linear copy)
        {
            const u16x8* gsrc = reinterpret_cast<const u16x8*>(w2T + (size_t)t * 16384);
            u16x8* ldst = reinterpret_cast<u16x8*>(sW2);
            #pragma unroll
            for (int it = 0; it < 8; ++it)
                ldst[tid + 256 * it] = gsrc[tid + 256 * it];
        }
        __syncthreads();
        #pragma unroll
        for (int ks = 0; ks < 4; ++ks) {
            bf16x8 af[4], bfr[4];
            #pragma unroll
            for (int ft = 0; ft < 4; ++ft)
                af[ft] = *reinterpret_cast<const bf16x8*>(&sW2[ks * 4096 + (64 * wf + 16 * ft + c) * 32 + 8 * g]);
            #pragma unroll
            for (int et = 0; et < 4; ++et)
                bfr[et] = *reinterpret_cast<const bf16x8*>(&sS[(64 * we + 16 * et + c) * 136 + ks * 32 + 8 * g]);
            #pragma unroll
            for (int ft = 0; ft < 4; ++ft)
                #pragma unroll
                for (int et = 0; et < 4; ++et)
                    acc[ft][et] = __builtin_amdgcn_mfma_f32_16x16x32_bf16(af[ft], bfr[et], acc[ft][et], 0, 0, 0);
        }
    }
    __syncthreads();   // MFMA reads of sS/sW2 done; rows[] may now overwrite them

    // epilogue: + XC + cnt*b2 -> rows[n][f] (fp32, stride 132)
    const unsigned int* x32 = reinterpret_cast<const unsigned int*>(xabc);
    #pragma unroll
    for (int et = 0; et < 4; ++et) {
        int n = 64 * we + 16 * et + c;
        int node = nb + n;
        if (node >= N_NODES) continue;
        float cnt4[N_TYPES];
        #pragma unroll
        for (int t = 0; t < N_TYPES; ++t)
            cnt4[t] = (float)(ptr[t * N_NODES + node + 1] - ptr[t * N_NODES + node]);
        #pragma unroll
        for (int ft = 0; ft < 4; ++ft) {
            int f0 = 64 * wf + 16 * ft + 4 * g;
            unsigned int xc0 = x32[(size_t)node * 576 + 512 + (f0 >> 1)];
            unsigned int xc1 = x32[(size_t)node * 576 + 512 + (f0 >> 1) + 1];
            float v[4];
            v[0] = acc[ft][et][0] + bf2f_lo(xc0);
            v[1] = acc[ft][et][1] + bf2f_hi(xc0);
            v[2] = acc[ft][et][2] + bf2f_lo(xc1);
            v[3] = acc[ft][et][3] + bf2f_hi(xc1);
            #pragma unroll
            for (int r = 0; r < 4; ++r) {
                float bs = 0.f;
                #pragma unroll
                for (int t = 0; t < N_TYPES; ++t)
                    bs = fmaf(cnt4[t], sB2[t * 128 + f0 + r], bs);
                v[r] += bs;
            }
            *reinterpret_cast<float4*>(&rows[n * 132 + f0]) = *reinterpret_cast<float4*>(v);
        }
    }
    __syncthreads();

    // ReLU + LN: each wave handles 32 rows
    for (int rr = 0; rr < 32; ++rr) {
        int r = w * 32 + rr;
        int node = nb + r;
        if (node >= N_NODES) break;
        float2 v = *reinterpret_cast<float2*>(&rows[r * 132 + lane * 2]);
        v.x = fmaxf(v.x, 0.f);
        v.y = fmaxf(v.y, 0.f);
        float s = v.x + v.y;
        float ss = v.x * v.x + v.y * v.y;
        #pragma unroll
        for (int m = 1; m < 64; m <<= 1) {
            s  += __shfl_xor(s, m, 64);
            ss += __shfl_xor(ss, m, 64);
        }
        float mu = s * (1.f / 128.f);
        float var = ss * (1.f / 128.f) - mu * mu;
        float rs = rsqrtf(var + LN_EPS);
        const float2 gm = *reinterpret_cast<const float2*>(gamma + lane * 2);
        const float2 bt = *reinterpret_cast<const float2*>(beta + lane * 2);
        float2 o;
        o.x = (v.x - mu) * rs * gm.x + bt.x;
        o.y = (v.y - mu) * rs * gm.y + bt.y;
        *reinterpret_cast<float2*>(out + (size_t)node * D_OUT + lane * 2) = o;
    }
}

extern "C" void kernel_launch(void* const* d_in, const int* in_sizes, int n_in,
                              void* d_out, int out_size, void* d_ws, size_t ws_size,
                              hipStream_t stream) {
    const float* x     = (const float*)d_in[0];
    const int*   ei    = (const int*)d_in[1];
    const int*   attr  = (const int*)d_in[2];
    const float* w1    = (const float*)d_in[3];
    const float* b1    = (const float*)d_in[4];
    const float* w2    = (const float*)d_in[5];
    const float* b2    = (const float*)d_in[6];
    const float* sw    = (const float*)d_in[7];
    const float* sb    = (const float*)d_in[8];
    const float* gamma = (const float*)d_in[9];
    const float* beta  = (const float*)d_in[10];
    float* out = (float*)d_out;

    if (ws_size < WS_TOTAL) return;   // fail visibly rather than corrupt

    char* ws = (char*)d_ws;
    int* cnt    = (int*)(ws + OFF_CNT);
    int* ptr    = (int*)(ws + OFF_PTR);
    int* cursor = (int*)(ws + OFF_CUR);
    int* bsum   = (int*)(ws + OFF_BSUM);
    int* boff   = (int*)(ws + OFF_BOFF);
    int* srows  = (int*)(ws + OFF_SROWS);
    unsigned short* xb    = (unsigned short*)(ws + OFF_XB);
    unsigned short* wcatT = (unsigned short*)(ws + OFF_WCAT);
    float*          bias  = (float*)(ws + OFF_BIAS);
    unsigned short* w2T   = (unsigned short*)(ws + OFF_W2T);
    unsigned short* xabc  = (unsigned short*)(ws + OFF_XABC);
    unsigned short* S     = (unsigned short*)(ws + OFF_S);

    hipMemsetAsync(cnt, 0, (size_t)N_BUCKETS * 4, stream);

    k_prep_all<<<NB_CVT + NB_PREP + NB_HIST, 256, 0, stream>>>(
        x, w1, sw, b1, sb, w2, ei, attr, xb, wcatT, bias, w2T, cnt);

    k_scanA<<<NSB, 256, 0, stream>>>(cnt, bsum);
    k_scanB<<<1, 256, 0, stream>>>(bsum, boff, ptr);
    k_scanC<<<NSB, 256, 0, stream>>>(cnt, boff, ptr, cursor);
    k_scatter2<<<(N_EDGES + 255) / 256, 256, 0, stream>>>(ei, attr, cursor, srows);

    k_gemm1<<<dim3((N_NODES + 127) / 128, NJT), 256, 0, stream>>>(xb, wcatT, bias, xabc);
    k_bucket<<<(N_BUCKETS + 3) / 4, 256, 0, stream>>>(xabc, ptr, srows, S);
    k_gemm2_ln<<<(N_NODES + 127) / 128, 256, 0, stream>>>(S, w2T, b2, xabc, ptr, gamma, beta, out);
}

// Round 7
// 228.779 us; speedup vs baseline: 3.1669x; 1.0246x over previous
//
#include <hip/hip_runtime.h>

#define N_NODES 50000
#define N_EDGES 800000
#define D_IN 128
#define D_OUT 128
#define N_TYPES 4
#define LN_EPS 1e-5f
#define N_BUCKETS (N_TYPES * N_NODES)   // 200000
#define NJT 9                            // 8 w1 halves + 1 self (self slab feeds gemm2)
#define SB_ITEMS 1024
#define NSB ((N_BUCKETS + SB_ITEMS - 1) / SB_ITEMS)   // 196

typedef __attribute__((ext_vector_type(4))) float f32x4;
typedef __attribute__((ext_vector_type(8))) __bf16 bf16x8;
typedef __attribute__((ext_vector_type(8))) unsigned short u16x8;

// ---- workspace layout (bytes), 256-aligned sections ----
constexpr size_t wsal(size_t x) { return (x + 255) & ~size_t(255); }
constexpr size_t OFF_CNT   = 0;                                              // 200000*4
constexpr size_t OFF_PTR   = OFF_CNT  + wsal((size_t)N_BUCKETS * 4);         // 200001*4
constexpr size_t OFF_CUR   = OFF_PTR  + wsal((size_t)(N_BUCKETS + 1) * 4);
constexpr size_t OFF_BSUM  = OFF_CUR  + wsal((size_t)N_BUCKETS * 4);         // 256*4
constexpr size_t OFF_SROWS = OFF_BSUM + wsal((size_t)256 * 4);               // 800000*4
constexpr size_t OFF_XB    = OFF_SROWS + wsal((size_t)N_EDGES * 4);          // 12.8MB
constexpr size_t OFF_WCAT  = OFF_XB   + wsal((size_t)N_NODES * D_IN * 2);    // 9*4*128*32*2
constexpr size_t OFF_BIAS  = OFF_WCAT + wsal((size_t)NJT * 4 * 128 * 32 * 2);
constexpr size_t OFF_W2T   = OFF_BIAS + wsal((size_t)NJT * 128 * 4);
constexpr size_t OFF_XABC  = OFF_W2T  + wsal((size_t)N_TYPES * 4 * 128 * 32 * 2);
constexpr size_t OFF_S     = OFF_XABC + wsal((size_t)8 * N_NODES * 128 * 2);    // 102.4MB
constexpr size_t WS_TOTAL  = OFF_S    + wsal((size_t)N_BUCKETS * 128 * 2);      // +51.2MB ≈ 172MB

__device__ __forceinline__ unsigned short f2bf(float f) {
    unsigned int u = __builtin_bit_cast(unsigned int, f);
    u += 0x7FFFu + ((u >> 16) & 1u);   // RNE; inputs finite
    return (unsigned short)(u >> 16);
}
__device__ __forceinline__ float bf2f_lo(unsigned int u) { return __builtin_bit_cast(float, u << 16); }
__device__ __forceinline__ float bf2f_hi(unsigned int u) { return __builtin_bit_cast(float, u & 0xFFFF0000u); }

// ---------------- merged prep: x->bf16 | weight transposes | (type,col) histogram ----------------
#define PREP_N0 (NJT * 4 * 128 * 32)
#define PREP_N1 (NJT * 128)
#define PREP_N2 (N_TYPES * 4 * 128 * 32)
#define NB_CVT  (N_NODES * D_IN / 4 / 256)                       // 6250 (exact)
#define NB_PREP ((PREP_N0 + PREP_N1 + PREP_N2 + 255) / 256)      // 837
#define NB_HIST ((N_EDGES + 255) / 256)                          // 3125

__global__ __launch_bounds__(256) void k_prep_all(
    const float* __restrict__ x,
    const float* __restrict__ w1, const float* __restrict__ sw,
    const float* __restrict__ b1, const float* __restrict__ sb,
    const float* __restrict__ w2,
    const int* __restrict__ ei, const int* __restrict__ attr,
    unsigned short* __restrict__ xb,
    unsigned short* __restrict__ wcatT, float* __restrict__ bias,
    unsigned short* __restrict__ w2T,
    int* __restrict__ cnt)
{
    const int bx = blockIdx.x;
    const int tid = threadIdx.x;
    if (bx < NB_CVT) {
        int i = bx * 256 + tid;
        const float4 v = reinterpret_cast<const float4*>(x)[i];
        ushort4 o;
        o.x = f2bf(v.x); o.y = f2bf(v.y); o.z = f2bf(v.z); o.w = f2bf(v.w);
        reinterpret_cast<ushort4*>(xb)[i] = o;
        return;
    }
    if (bx < NB_CVT + NB_PREP) {
        int gid = (bx - NB_CVT) * 256 + tid;
        if (gid < PREP_N0) {
            // wcatT[jt][ks][jm][kk] = Wcat[ks*32+kk][jt*128+jm]
            int kk = gid & 31;
            int jm = (gid >> 5) & 127;
            int ks = (gid >> 12) & 3;
            int jt = gid >> 14;
            int k  = ks * 32 + kk;
            float v;
            if (jt < 8) {
                int t = jt >> 1, half = jt & 1;
                v = w1[((size_t)t * 256 + half * 128 + k) * 128 + jm];
            } else {
                v = sw[(size_t)k * 128 + jm];
            }
            wcatT[gid] = f2bf(v);
            return;
        }
        gid -= PREP_N0;
        if (gid < PREP_N1) {
            int jt = gid >> 7, jm = gid & 127;
            float v = 0.f;
            if (jt < 8) { if (jt & 1) v = b1[(jt >> 1) * 128 + jm]; }
            else v = sb[jm];
            bias[gid] = v;
            return;
        }
        gid -= PREP_N1;
        if (gid < PREP_N2) {
            // w2T[t][ks][f][kk] = w2[t][ks*32+kk][f]
            int kk = gid & 31;
            int f  = (gid >> 5) & 127;
            int ks = (gid >> 12) & 3;
            int t  = gid >> 14;
            float v = w2[((size_t)t * 128 + ks * 32 + kk) * 128 + f];
            w2T[gid] = f2bf(v);
        }
        return;
    }
    {
        int e = (bx - NB_CVT - NB_PREP) * 256 + tid;
        if (e < N_EDGES) {
            int t = attr[e];
            int c = ei[N_EDGES + e];
            atomicAdd(&cnt[t * N_NODES + c], 1);
        }
    }
}

// ---- 2-phase device-wide exclusive scan over cnt[200000] ----
__global__ __launch_bounds__(256) void k_scanA(const int* __restrict__ cnt, int* __restrict__ bsum) {
    __shared__ int red[256];
    const int b = blockIdx.x, tid = threadIdx.x;
    const int base = b * SB_ITEMS + tid * 4;
    int s = 0;
    if (base + 3 < N_BUCKETS) {
        const int4 v = *reinterpret_cast<const int4*>(cnt + base);
        s = v.x + v.y + v.z + v.w;
    } else {
        #pragma unroll
        for (int i = 0; i < 4; ++i) if (base + i < N_BUCKETS) s += cnt[base + i];
    }
    red[tid] = s;
    __syncthreads();
    #pragma unroll
    for (int d = 128; d > 0; d >>= 1) {
        if (tid < d) red[tid] += red[tid + d];
        __syncthreads();
    }
    if (tid == 0) bsum[b] = red[0];
}

// scanC: redundant per-block scan of bsum (replaces scanB) + per-item scan
__global__ __launch_bounds__(256) void k_scanC(const int* __restrict__ cnt,
                                               const int* __restrict__ bsum,
                                               int* __restrict__ ptr,
                                               int* __restrict__ cursor) {
    __shared__ int sc[256];
    const int b = blockIdx.x, tid = threadIdx.x;
    // phase 1: exclusive prefix of block sums, take our block's offset
    int bv = (tid < NSB) ? bsum[tid] : 0;
    sc[tid] = bv;
    __syncthreads();
    #pragma unroll
    for (int d = 1; d < 256; d <<= 1) {
        int add = (tid >= d) ? sc[tid - d] : 0;
        __syncthreads();
        sc[tid] += add;
        __syncthreads();
    }
    const int blockOff = (b > 0) ? sc[b - 1] : 0;
    __syncthreads();
    // phase 2: item scan within block
    const int base = b * SB_ITEMS + tid * 4;
    int v[4] = {0, 0, 0, 0};
    if (base + 3 < N_BUCKETS) {
        const int4 t4 = *reinterpret_cast<const int4*>(cnt + base);
        v[0] = t4.x; v[1] = t4.y; v[2] = t4.z; v[3] = t4.w;
    } else {
        #pragma unroll
        for (int i = 0; i < 4; ++i) if (base + i < N_BUCKETS) v[i] = cnt[base + i];
    }
    const int s = v[0] + v[1] + v[2] + v[3];
    sc[tid] = s;
    __syncthreads();
    #pragma unroll
    for (int d = 1; d < 256; d <<= 1) {
        int add = (tid >= d) ? sc[tid - d] : 0;
        __syncthreads();
        sc[tid] += add;
        __syncthreads();
    }
    int run = blockOff + sc[tid] - s;
    #pragma unroll
    for (int i = 0; i < 4; ++i) {
        if (base + i < N_BUCKETS) {
            ptr[base + i] = run;
            cursor[base + i] = run;
            run += v[i];
        }
    }
    if (b == 0 && tid == 0) ptr[N_BUCKETS] = N_EDGES;
}

// srows[pos] = source-row of the edge, grouped by (type, col)
__global__ void k_scatter2(const int* __restrict__ ei, const int* __restrict__ attr,
                           int* __restrict__ cursor, int* __restrict__ srows) {
    int e = blockIdx.x * blockDim.x + threadIdx.x;
    if (e >= N_EDGES) return;
    int t = attr[e];
    int c = ei[N_EDGES + e];
    int pos = atomicAdd(&cursor[t * N_NODES + c], 1);
    srows[pos] = ei[e];
}

// ---------------- GEMM1: slab jt of XAB[jt][n][128] = xb[n] @ Wcat_jt + bias_jt  (bf16, 8 slabs) ----------------
__global__ __launch_bounds__(256, 2) void k_gemm1(
    const unsigned short* __restrict__ xb,
    const unsigned short* __restrict__ wcatT,
    const float* __restrict__ bias,
    unsigned short* __restrict__ xab)
{
    const int nb = blockIdx.x * 128;
    const int jt = blockIdx.y;

    __shared__ __align__(16) unsigned short sX[128 * 136];  // x rows [n][k], pad 136; reused as out tile [n][j]
    __shared__ __align__(16) unsigned short sW[4 * 128 * 32]; // full per-jt weight slab (32KB)

    const int tid = threadIdx.x;
    const int lane = tid & 63;
    const int w = tid >> 6;
    const int g = lane >> 4;
    const int c = lane & 15;
    const int wf = w >> 1;   // j half
    const int we = w & 1;    // n half

    // stage x rows (coalesced; clamp OOB rows)
    #pragma unroll
    for (int it = 0; it < 8; ++it) {
        int row = 16 * it + (tid >> 4);
        int node = min(nb + row, N_NODES - 1);
        const u16x8 v = *reinterpret_cast<const u16x8*>(xb + (size_t)node * D_IN + (tid & 15) * 8);
        *reinterpret_cast<u16x8*>(&sX[row * 136 + (tid & 15) * 8]) = v;
    }
    // stage full weight slab for this jt
    {
        const u16x8* gsrc = reinterpret_cast<const u16x8*>(wcatT + (size_t)jt * 16384);
        u16x8* ldst = reinterpret_cast<u16x8*>(sW);
        #pragma unroll
        for (int it = 0; it < 8; ++it)
            ldst[tid + 256 * it] = gsrc[tid + 256 * it];
    }

    f32x4 acc[4][4];
    #pragma unroll
    for (int ft = 0; ft < 4; ++ft)
        #pragma unroll
        for (int et = 0; et < 4; ++et)
            acc[ft][et] = f32x4{0.f, 0.f, 0.f, 0.f};

    __syncthreads();

    #pragma unroll
    for (int ks = 0; ks < 4; ++ks) {
        bf16x8 af[4], bfr[4];
        #pragma unroll
        for (int ft = 0; ft < 4; ++ft)
            af[ft] = *reinterpret_cast<const bf16x8*>(&sW[ks * 4096 + (64 * wf + 16 * ft + c) * 32 + 8 * g]);
        #pragma unroll
        for (int et = 0; et < 4; ++et)
            bfr[et] = *reinterpret_cast<const bf16x8*>(&sX[(64 * we + 16 * et + c) * 136 + ks * 32 + 8 * g]);
        #pragma unroll
        for (int ft = 0; ft < 4; ++ft)
            #pragma unroll
            for (int et = 0; et < 4; ++et)
                acc[ft][et] = __builtin_amdgcn_mfma_f32_16x16x32_bf16(af[ft], bfr[et], acc[ft][et], 0, 0, 0);
    }
    __syncthreads();   // sX reads done; reuse as output tile

    // + bias, pack bf16 -> sX as [n][j] (u32 pairs)
    {
        float bv[4][4];
        #pragma unroll
        for (int ft = 0; ft < 4; ++ft)
            #pragma unroll
            for (int r = 0; r < 4; ++r)
                bv[ft][r] = bias[jt * 128 + 64 * wf + 16 * ft + 4 * g + r];
        unsigned int* so = reinterpret_cast<unsigned int*>(sX);
        #pragma unroll
        for (int ft = 0; ft < 4; ++ft) {
            #pragma unroll
            for (int et = 0; et < 4; ++et) {
                int n = 64 * we + 16 * et + c;
                int jb = 32 * wf + 8 * ft + 2 * g;   // u32 index within row
                float v0 = acc[ft][et][0] + bv[ft][0];
                float v1 = acc[ft][et][1] + bv[ft][1];
                float v2 = acc[ft][et][2] + bv[ft][2];
                float v3 = acc[ft][et][3] + bv[ft][3];
                so[n * 68 + jb + 0] = (unsigned int)f2bf(v0) | ((unsigned int)f2bf(v1) << 16);
                so[n * 68 + jb + 1] = (unsigned int)f2bf(v2) | ((unsigned int)f2bf(v3) << 16);
            }
        }
    }
    __syncthreads();

    // coalesced write to slab
    #pragma unroll
    for (int it = 0; it < 8; ++it) {
        int row = 16 * it + (tid >> 4);
        int node = nb + row;
        if (node < N_NODES) {
            const u16x8 v = *reinterpret_cast<const u16x8*>(&sX[row * 136 + (tid & 15) * 8]);
            *reinterpret_cast<u16x8*>(xab + ((size_t)jt * N_NODES + node) * 128 + (tid & 15) * 8) = v;
        }
    }
}

// ---------------- bucket aggregation: S[t*N+n] = sum_{e in (t,n)} relu(XA_t[row_e] + XB_t[n]) ----------------
// Predicated 8-wide batches: EVERY bucket runs <=ceil(cnt/8) batches of 8 clamped gathers
// (3 dependent memory epochs per batch: srows -> gathers -> acc), no serial remainder chain.
__global__ __launch_bounds__(256) void k_bucket(const unsigned short* __restrict__ xab,
                                                const int* __restrict__ ptr,
                                                const int* __restrict__ srows,
                                                unsigned short* __restrict__ S)
{
    const int b = blockIdx.x * 4 + (threadIdx.x >> 6);
    if (b >= N_BUCKETS) return;
    const int lane = threadIdx.x & 63;
    const int t = b / N_NODES;
    const int n = b - t * N_NODES;
    const int s = ptr[b], e = ptr[b + 1];
    const unsigned int* x32 = reinterpret_cast<const unsigned int*>(xab);
    float a0 = 0.f, a1 = 0.f;
    if (s < e) {
        const unsigned int xbv = x32[((size_t)(2 * t + 1) * N_NODES + n) * 64 + lane];  // XB_t[n] (+b1 baked)
        const float xb0 = bf2f_lo(xbv), xb1 = bf2f_hi(xbv);
        const size_t xaBase = (size_t)(2 * t) * N_NODES * 64 + lane;
        for (int j = s; j < e; j += 8) {
            int idx[8];
            unsigned int vv[8];
            #pragma unroll
            for (int i = 0; i < 8; ++i)
                idx[i] = srows[min(j + i, e - 1)];
            #pragma unroll
            for (int i = 0; i < 8; ++i)
                vv[i] = x32[xaBase + (size_t)idx[i] * 64];
            #pragma unroll
            for (int i = 0; i < 8; ++i) {
                bool on = (j + i) < e;
                float h0 = fmaxf(bf2f_lo(vv[i]) + xb0, 0.f);
                float h1 = fmaxf(bf2f_hi(vv[i]) + xb1, 0.f);
                a0 += on ? h0 : 0.f;
                a1 += on ? h1 : 0.f;
            }
        }
    }
    reinterpret_cast<unsigned int*>(S)[(size_t)b * 64 + lane] =
        (unsigned int)f2bf(a0) | ((unsigned int)f2bf(a1) << 16);
}

// ---------------- GEMM2 (+self-proj) + ReLU + LayerNorm fused ----------------
// out[n] = LN(relu(x[n]@SW + sb + sum_t S_t[n] @ W2_t + sum_t cnt_{t,n} * b2_t))
__global__ __launch_bounds__(256, 2) void k_gemm2_ln(
    const unsigned short* __restrict__ S,
    const unsigned short* __restrict__ w2T,
    const unsigned short* __restrict__ wcatT,   // slab 8 = self weights
    const unsigned short* __restrict__ xb,
    const float* __restrict__ b2,
    const float* __restrict__ sb,
    const int* __restrict__ ptr,
    const float* __restrict__ gamma,
    const float* __restrict__ beta,
    float* __restrict__ out)
{
    const int nb = blockIdx.x * 128;
    // manual shared layout so the fp32 row buffer can alias sS+sW2 after MFMA
    __shared__ __align__(16) unsigned char sm[128 * 136 * 2 + 4 * 128 * 32 * 2 + 512 * 4];
    unsigned short* sS  = reinterpret_cast<unsigned short*>(sm);               // [128*136]
    unsigned short* sW2 = reinterpret_cast<unsigned short*>(sm + 34816);       // [4*128*32]
    float* sB2          = reinterpret_cast<float*>(sm + 34816 + 32768);        // [512]
    float* rows         = reinterpret_cast<float*>(sm);                        // [128][132] alias, used post-MFMA

    const int tid = threadIdx.x;
    const int lane = tid & 63;
    const int w = tid >> 6;
    const int g = lane >> 4;
    const int c = lane & 15;
    const int wf = w >> 1;   // f half
    const int we = w & 1;    // n half

    sB2[tid] = b2[tid];
    sB2[tid + 256] = b2[tid + 256];

    f32x4 acc[4][4];
    #pragma unroll
    for (int ft = 0; ft < 4; ++ft)
        #pragma unroll
        for (int et = 0; et < 4; ++et)
            acc[ft][et] = f32x4{0.f, 0.f, 0.f, 0.f};

    for (int t = 0; t < 5; ++t) {
        const unsigned short* srcS = (t < 4) ? S + (size_t)t * N_NODES * 128 : xb;
        const unsigned short* srcW = (t < 4) ? w2T + (size_t)t * 16384 : wcatT + (size_t)8 * 16384;
        __syncthreads();   // prev reads done before restage
        // stage input tile (coalesced, clamp)
        #pragma unroll
        for (int it = 0; it < 8; ++it) {
            int row = 16 * it + (tid >> 4);
            int node = min(nb + row, N_NODES - 1);
            const u16x8 v = *reinterpret_cast<const u16x8*>(srcS + (size_t)node * 128 + (tid & 15) * 8);
            *reinterpret_cast<u16x8*>(&sS[row * 136 + (tid & 15) * 8]) = v;
        }
        // stage full weight slab (linear copy)
        {
            const u16x8* gsrc = reinterpret_cast<const u16x8*>(srcW);
            u16x8* ldst = reinterpret_cast<u16x8*>(sW2);
            #pragma unroll
            for (int it = 0; it < 8; ++it)
                ldst[tid + 256 * it] = gsrc[tid + 256 * it];
        }
        __syncthreads();
        #pragma unroll
        for (int ks = 0; ks < 4; ++ks) {
            bf16x8 af[4], bfr[4];
            #pragma unroll
            for (int ft = 0; ft < 4; ++ft)
                af[ft] = *reinterpret_cast<const bf16x8*>(&sW2[ks * 4096 + (64 * wf + 16 * ft + c) * 32 + 8 * g]);
            #pragma unroll
            for (int et = 0; et < 4; ++et)
                bfr[et] = *reinterpret_cast<const bf16x8*>(&sS[(64 * we + 16 * et + c) * 136 + ks * 32 + 8 * g]);
            #pragma unroll
            for (int ft = 0; ft < 4; ++ft)
                #pragma unroll
                for (int et = 0; et < 4; ++et)
                    acc[ft][et] = __builtin_amdgcn_mfma_f32_16x16x32_bf16(af[ft], bfr[et], acc[ft][et], 0, 0, 0);
        }
    }
    __syncthreads();   // MFMA reads of sS/sW2 done; rows[] may now overwrite them

    // epilogue: + sb + cnt*b2 -> rows[n][f] (fp32, stride 132)
    #pragma unroll
    for (int et = 0; et < 4; ++et) {
        int n = 64 * we + 16 * et + c;
        int node = nb + n;
        if (node >= N_NODES) continue;
        float cnt4[N_TYPES];
        #pragma unroll
        for (int t = 0; t < N_TYPES; ++t)
            cnt4[t] = (float)(ptr[t * N_NODES + node + 1] - ptr[t * N_NODES + node]);
        #pragma unroll
        for (int ft = 0; ft < 4; ++ft) {
            int f0 = 64 * wf + 16 * ft + 4 * g;
            const float4 sbv = *reinterpret_cast<const float4*>(sb + f0);
            float v[4];
            v[0] = acc[ft][et][0] + sbv.x;
            v[1] = acc[ft][et][1] + sbv.y;
            v[2] = acc[ft][et][2] + sbv.z;
            v[3] = acc[ft][et][3] + sbv.w;
            #pragma unroll
            for (int r = 0; r < 4; ++r) {
                float bs = 0.f;
                #pragma unroll
                for (int t = 0; t < N_TYPES; ++t)
                    bs = fmaf(cnt4[t], sB2[t * 128 + f0 + r], bs);
                v[r] += bs;
            }
            *reinterpret_cast<float4*>(&rows[n * 132 + f0]) = *reinterpret_cast<float4*>(v);
        }
    }
    __syncthreads();

    // ReLU + LN: each wave handles 32 rows
    for (int rr = 0; rr < 32; ++rr) {
        int r = w * 32 + rr;
        int node = nb + r;
        if (node >= N_NODES) break;
        float2 v = *reinterpret_cast<float2*>(&rows[r * 132 + lane * 2]);
        v.x = fmaxf(v.x, 0.f);
        v.y = fmaxf(v.y, 0.f);
        float s = v.x + v.y;
        float ss = v.x * v.x + v.y * v.y;
        #pragma unroll
        for (int m = 1; m < 64; m <<= 1) {
            s  += __shfl_xor(s, m, 64);
            ss += __shfl_xor(ss, m, 64);
        }
        float mu = s * (1.f / 128.f);
        float var = ss * (1.f / 128.f) - mu * mu;
        float rs = rsqrtf(var + LN_EPS);
        const float2 gm = *reinterpret_cast<const float2*>(gamma + lane * 2);
        const float2 bt = *reinterpret_cast<const float2*>(beta + lane * 2);
        float2 o;
        o.x = (v.x - mu) * rs * gm.x + bt.x;
        o.y = (v.y - mu) * rs * gm.y + bt.y;
        *reinterpret_cast<float2*>(out + (size_t)node * D_OUT + lane * 2) = o;
    }
}

extern "C" void kernel_launch(void* const* d_in, const int* in_sizes, int n_in,
                              void* d_out, int out_size, void* d_ws, size_t ws_size,
                              hipStream_t stream) {
    const float* x     = (const float*)d_in[0];
    const int*   ei    = (const int*)d_in[1];
    const int*   attr  = (const int*)d_in[2];
    const float* w1    = (const float*)d_in[3];
    const float* b1    = (const float*)d_in[4];
    const float* w2    = (const float*)d_in[5];
    const float* b2    = (const float*)d_in[6];
    const float* sw    = (const float*)d_in[7];
    const float* sb    = (const float*)d_in[8];
    const float* gamma = (const float*)d_in[9];
    const float* beta  = (const float*)d_in[10];
    float* out = (float*)d_out;

    if (ws_size < WS_TOTAL) return;   // fail visibly rather than corrupt

    char* ws = (char*)d_ws;
    int* cnt    = (int*)(ws + OFF_CNT);
    int* ptr    = (int*)(ws + OFF_PTR);
    int* cursor = (int*)(ws + OFF_CUR);
    int* bsum   = (int*)(ws + OFF_BSUM);
    int* srows  = (int*)(ws + OFF_SROWS);
    unsigned short* xb    = (unsigned short*)(ws + OFF_XB);
    unsigned short* wcatT = (unsigned short*)(ws + OFF_WCAT);
    float*          bias  = (float*)(ws + OFF_BIAS);
    unsigned short* w2T   = (unsigned short*)(ws + OFF_W2T);
    unsigned short* xab   = (unsigned short*)(ws + OFF_XABC);
    unsigned short* S     = (unsigned short*)(ws + OFF_S);

    hipMemsetAsync(cnt, 0, (size_t)N_BUCKETS * 4, stream);

    k_prep_all<<<NB_CVT + NB_PREP + NB_HIST, 256, 0, stream>>>(
        x, w1, sw, b1, sb, w2, ei, attr, xb, wcatT, bias, w2T, cnt);

    k_scanA<<<NSB, 256, 0, stream>>>(cnt, bsum);
    k_scanC<<<NSB, 256, 0, stream>>>(cnt, bsum, ptr, cursor);
    k_scatter2<<<(N_EDGES + 255) / 256, 256, 0, stream>>>(ei, attr, cursor, srows);

    k_gemm1<<<dim3((N_NODES + 127) / 128, 8), 256, 0, stream>>>(xb, wcatT, bias, xab);
    k_bucket<<<(N_BUCKETS + 3) / 4, 256, 0, stream>>>(xab, ptr, srows, S);
    k_gemm2_ln<<<(N_NODES + 127) / 128, 256, 0, stream>>>(
        S, w2T, wcatT, xb, b2, sb, ptr, gamma, beta, out);
}

// Round 8
// 211.353 us; speedup vs baseline: 3.4280x; 1.0825x over previous
//
#include <hip/hip_runtime.h>

#define N_NODES 50000
#define N_EDGES 800000
#define D_IN 128
#define D_OUT 128
#define N_TYPES 4
#define LN_EPS 1e-5f
#define N_BUCKETS (N_TYPES * N_NODES)   // 200000, keyed as node*4+type
#define NJT 9                            // 8 w1 halves + 1 self (self slab feeds gemm2)
#define SB_ITEMS 1024
#define NSB ((N_BUCKETS + SB_ITEMS - 1) / SB_ITEMS)   // 196

typedef __attribute__((ext_vector_type(4))) float f32x4;
typedef __attribute__((ext_vector_type(8))) __bf16 bf16x8;
typedef __attribute__((ext_vector_type(8))) unsigned short u16x8;

// ---- workspace layout (bytes), 256-aligned sections ----
constexpr size_t wsal(size_t x) { return (x + 255) & ~size_t(255); }
constexpr size_t OFF_CNT   = 0;                                              // 200000*4
constexpr size_t OFF_PTR   = OFF_CNT  + wsal((size_t)N_BUCKETS * 4);         // 200001*4
constexpr size_t OFF_CUR   = OFF_PTR  + wsal((size_t)(N_BUCKETS + 1) * 4);
constexpr size_t OFF_BSUM  = OFF_CUR  + wsal((size_t)N_BUCKETS * 4);         // 256*4
constexpr size_t OFF_SROWS = OFF_BSUM + wsal((size_t)256 * 4);               // 800000*4
constexpr size_t OFF_XB    = OFF_SROWS + wsal((size_t)N_EDGES * 4);          // 12.8MB
constexpr size_t OFF_WCAT  = OFF_XB   + wsal((size_t)N_NODES * D_IN * 2);    // 9*4*128*32*2
constexpr size_t OFF_BIAS  = OFF_WCAT + wsal((size_t)NJT * 4 * 128 * 32 * 2);
constexpr size_t OFF_W2T   = OFF_BIAS + wsal((size_t)NJT * 128 * 4);
constexpr size_t OFF_XABC  = OFF_W2T  + wsal((size_t)N_TYPES * 4 * 128 * 32 * 2);
constexpr size_t OFF_S     = OFF_XABC + wsal((size_t)8 * N_NODES * 128 * 2);    // 102.4MB
constexpr size_t WS_TOTAL  = OFF_S    + wsal((size_t)N_BUCKETS * 128 * 2);      // +51.2MB ≈ 172MB

__device__ __forceinline__ unsigned short f2bf(float f) {
    unsigned int u = __builtin_bit_cast(unsigned int, f);
    u += 0x7FFFu + ((u >> 16) & 1u);   // RNE; inputs finite
    return (unsigned short)(u >> 16);
}
__device__ __forceinline__ float bf2f_lo(unsigned int u) { return __builtin_bit_cast(float, u << 16); }
__device__ __forceinline__ float bf2f_hi(unsigned int u) { return __builtin_bit_cast(float, u & 0xFFFF0000u); }

// ---------------- merged prep: x->bf16 | weight transposes | (col,type) histogram ----------------
#define PREP_N0 (NJT * 4 * 128 * 32)
#define PREP_N1 (NJT * 128)
#define PREP_N2 (N_TYPES * 4 * 128 * 32)
#define NB_CVT  (N_NODES * D_IN / 4 / 256)                       // 6250 (exact)
#define NB_PREP ((PREP_N0 + PREP_N1 + PREP_N2 + 255) / 256)      // 837
#define NB_HIST ((N_EDGES + 255) / 256)                          // 3125

__global__ __launch_bounds__(256) void k_prep_all(
    const float* __restrict__ x,
    const float* __restrict__ w1, const float* __restrict__ sw,
    const float* __restrict__ b1, const float* __restrict__ sb,
    const float* __restrict__ w2,
    const int* __restrict__ ei, const int* __restrict__ attr,
    unsigned short* __restrict__ xb,
    unsigned short* __restrict__ wcatT, float* __restrict__ bias,
    unsigned short* __restrict__ w2T,
    int* __restrict__ cnt)
{
    const int bx = blockIdx.x;
    const int tid = threadIdx.x;
    if (bx < NB_CVT) {
        int i = bx * 256 + tid;
        const float4 v = reinterpret_cast<const float4*>(x)[i];
        ushort4 o;
        o.x = f2bf(v.x); o.y = f2bf(v.y); o.z = f2bf(v.z); o.w = f2bf(v.w);
        reinterpret_cast<ushort4*>(xb)[i] = o;
        return;
    }
    if (bx < NB_CVT + NB_PREP) {
        int gid = (bx - NB_CVT) * 256 + tid;
        if (gid < PREP_N0) {
            // wcatT[jt][ks][jm][kk] = Wcat[ks*32+kk][jt*128+jm]
            int kk = gid & 31;
            int jm = (gid >> 5) & 127;
            int ks = (gid >> 12) & 3;
            int jt = gid >> 14;
            int k  = ks * 32 + kk;
            float v;
            if (jt < 8) {
                int t = jt >> 1, half = jt & 1;
                v = w1[((size_t)t * 256 + half * 128 + k) * 128 + jm];
            } else {
                v = sw[(size_t)k * 128 + jm];
            }
            wcatT[gid] = f2bf(v);
            return;
        }
        gid -= PREP_N0;
        if (gid < PREP_N1) {
            int jt = gid >> 7, jm = gid & 127;
            float v = 0.f;
            if (jt < 8) { if (jt & 1) v = b1[(jt >> 1) * 128 + jm]; }
            else v = sb[jm];
            bias[gid] = v;
            return;
        }
        gid -= PREP_N1;
        if (gid < PREP_N2) {
            // w2T[t][ks][f][kk] = w2[t][ks*32+kk][f]
            int kk = gid & 31;
            int f  = (gid >> 5) & 127;
            int ks = (gid >> 12) & 3;
            int t  = gid >> 14;
            float v = w2[((size_t)t * 128 + ks * 32 + kk) * 128 + f];
            w2T[gid] = f2bf(v);
        }
        return;
    }
    {
        int e = (bx - NB_CVT - NB_PREP) * 256 + tid;
        if (e < N_EDGES) {
            int t = attr[e];
            int c = ei[N_EDGES + e];
            atomicAdd(&cnt[c * 4 + t], 1);
        }
    }
}

// ---- 2-phase device-wide exclusive scan over cnt[200000] ----
__global__ __launch_bounds__(256) void k_scanA(const int* __restrict__ cnt, int* __restrict__ bsum) {
    __shared__ int red[256];
    const int b = blockIdx.x, tid = threadIdx.x;
    const int base = b * SB_ITEMS + tid * 4;
    int s = 0;
    if (base + 3 < N_BUCKETS) {
        const int4 v = *reinterpret_cast<const int4*>(cnt + base);
        s = v.x + v.y + v.z + v.w;
    } else {
        #pragma unroll
        for (int i = 0; i < 4; ++i) if (base + i < N_BUCKETS) s += cnt[base + i];
    }
    red[tid] = s;
    __syncthreads();
    #pragma unroll
    for (int d = 128; d > 0; d >>= 1) {
        if (tid < d) red[tid] += red[tid + d];
        __syncthreads();
    }
    if (tid == 0) bsum[b] = red[0];
}

// scanC: redundant per-block scan of bsum + per-item scan
__global__ __launch_bounds__(256) void k_scanC(const int* __restrict__ cnt,
                                               const int* __restrict__ bsum,
                                               int* __restrict__ ptr,
                                               int* __restrict__ cursor) {
    __shared__ int sc[256];
    const int b = blockIdx.x, tid = threadIdx.x;
    int bv = (tid < NSB) ? bsum[tid] : 0;
    sc[tid] = bv;
    __syncthreads();
    #pragma unroll
    for (int d = 1; d < 256; d <<= 1) {
        int add = (tid >= d) ? sc[tid - d] : 0;
        __syncthreads();
        sc[tid] += add;
        __syncthreads();
    }
    const int blockOff = (b > 0) ? sc[b - 1] : 0;
    __syncthreads();
    const int base = b * SB_ITEMS + tid * 4;
    int v[4] = {0, 0, 0, 0};
    if (base + 3 < N_BUCKETS) {
        const int4 t4 = *reinterpret_cast<const int4*>(cnt + base);
        v[0] = t4.x; v[1] = t4.y; v[2] = t4.z; v[3] = t4.w;
    } else {
        #pragma unroll
        for (int i = 0; i < 4; ++i) if (base + i < N_BUCKETS) v[i] = cnt[base + i];
    }
    const int s = v[0] + v[1] + v[2] + v[3];
    sc[tid] = s;
    __syncthreads();
    #pragma unroll
    for (int d = 1; d < 256; d <<= 1) {
        int add = (tid >= d) ? sc[tid - d] : 0;
        __syncthreads();
        sc[tid] += add;
        __syncthreads();
    }
    int run = blockOff + sc[tid] - s;
    #pragma unroll
    for (int i = 0; i < 4; ++i) {
        if (base + i < N_BUCKETS) {
            ptr[base + i] = run;
            cursor[base + i] = run;
            run += v[i];
        }
    }
    if (b == 0 && tid == 0) ptr[N_BUCKETS] = N_EDGES;
}

// srows[pos] = ABSOLUTE XA slab row (2t*N + srcRow), grouped by (col, type)
__global__ void k_scatter2(const int* __restrict__ ei, const int* __restrict__ attr,
                           int* __restrict__ cursor, int* __restrict__ srows) {
    int e = blockIdx.x * blockDim.x + threadIdx.x;
    if (e >= N_EDGES) return;
    int t = attr[e];
    int c = ei[N_EDGES + e];
    int pos = atomicAdd(&cursor[c * 4 + t], 1);
    srows[pos] = 2 * t * N_NODES + ei[e];
}

// ---------------- GEMM1: slab jt of XAB[jt][n][128] = xb[n] @ Wcat_jt + bias_jt  (bf16, 8 slabs) ----------------
__global__ __launch_bounds__(256, 2) void k_gemm1(
    const unsigned short* __restrict__ xb,
    const unsigned short* __restrict__ wcatT,
    const float* __restrict__ bias,
    unsigned short* __restrict__ xab)
{
    const int nb = blockIdx.x * 128;
    const int jt = blockIdx.y;

    __shared__ __align__(16) unsigned short sX[128 * 136];  // x rows [n][k], pad 136; reused as out tile [n][j]
    __shared__ __align__(16) unsigned short sW[4 * 128 * 32]; // full per-jt weight slab (32KB)

    const int tid = threadIdx.x;
    const int lane = tid & 63;
    const int w = tid >> 6;
    const int g = lane >> 4;
    const int c = lane & 15;
    const int wf = w >> 1;   // j half
    const int we = w & 1;    // n half

    #pragma unroll
    for (int it = 0; it < 8; ++it) {
        int row = 16 * it + (tid >> 4);
        int node = min(nb + row, N_NODES - 1);
        const u16x8 v = *reinterpret_cast<const u16x8*>(xb + (size_t)node * D_IN + (tid & 15) * 8);
        *reinterpret_cast<u16x8*>(&sX[row * 136 + (tid & 15) * 8]) = v;
    }
    {
        const u16x8* gsrc = reinterpret_cast<const u16x8*>(wcatT + (size_t)jt * 16384);
        u16x8* ldst = reinterpret_cast<u16x8*>(sW);
        #pragma unroll
        for (int it = 0; it < 8; ++it)
            ldst[tid + 256 * it] = gsrc[tid + 256 * it];
    }

    f32x4 acc[4][4];
    #pragma unroll
    for (int ft = 0; ft < 4; ++ft)
        #pragma unroll
        for (int et = 0; et < 4; ++et)
            acc[ft][et] = f32x4{0.f, 0.f, 0.f, 0.f};

    __syncthreads();

    #pragma unroll
    for (int ks = 0; ks < 4; ++ks) {
        bf16x8 af[4], bfr[4];
        #pragma unroll
        for (int ft = 0; ft < 4; ++ft)
            af[ft] = *reinterpret_cast<const bf16x8*>(&sW[ks * 4096 + (64 * wf + 16 * ft + c) * 32 + 8 * g]);
        #pragma unroll
        for (int et = 0; et < 4; ++et)
            bfr[et] = *reinterpret_cast<const bf16x8*>(&sX[(64 * we + 16 * et + c) * 136 + ks * 32 + 8 * g]);
        #pragma unroll
        for (int ft = 0; ft < 4; ++ft)
            #pragma unroll
            for (int et = 0; et < 4; ++et)
                acc[ft][et] = __builtin_amdgcn_mfma_f32_16x16x32_bf16(af[ft], bfr[et], acc[ft][et], 0, 0, 0);
    }
    __syncthreads();   // sX reads done; reuse as output tile

    {
        float bv[4][4];
        #pragma unroll
        for (int ft = 0; ft < 4; ++ft)
            #pragma unroll
            for (int r = 0; r < 4; ++r)
                bv[ft][r] = bias[jt * 128 + 64 * wf + 16 * ft + 4 * g + r];
        unsigned int* so = reinterpret_cast<unsigned int*>(sX);
        #pragma unroll
        for (int ft = 0; ft < 4; ++ft) {
            #pragma unroll
            for (int et = 0; et < 4; ++et) {
                int n = 64 * we + 16 * et + c;
                int jb = 32 * wf + 8 * ft + 2 * g;
                float v0 = acc[ft][et][0] + bv[ft][0];
                float v1 = acc[ft][et][1] + bv[ft][1];
                float v2 = acc[ft][et][2] + bv[ft][2];
                float v3 = acc[ft][et][3] + bv[ft][3];
                so[n * 68 + jb + 0] = (unsigned int)f2bf(v0) | ((unsigned int)f2bf(v1) << 16);
                so[n * 68 + jb + 1] = (unsigned int)f2bf(v2) | ((unsigned int)f2bf(v3) << 16);
            }
        }
    }
    __syncthreads();

    #pragma unroll
    for (int it = 0; it < 8; ++it) {
        int row = 16 * it + (tid >> 4);
        int node = nb + row;
        if (node < N_NODES) {
            const u16x8 v = *reinterpret_cast<const u16x8*>(&sX[row * 136 + (tid & 15) * 8]);
            *reinterpret_cast<u16x8*>(xab + ((size_t)jt * N_NODES + node) * 128 + (tid & 15) * 8) = v;
        }
    }
}

// ---------------- node-major aggregation: one wave per node, all 4 types ----------------
// S[n][t] = sum over (col,type) segment of relu(XA_abs[row] + XB_t[n]); S node-major [n][4][128] bf16.
__global__ __launch_bounds__(256) void k_agg(const unsigned short* __restrict__ xab,
                                             const int* __restrict__ ptr,
                                             const int* __restrict__ srows,
                                             unsigned short* __restrict__ S)
{
    const int n = (blockIdx.x * 256 + threadIdx.x) >> 6;   // node = global wave id
    if (n >= N_NODES) return;
    const int lane = threadIdx.x & 63;
    const unsigned int* x32 = reinterpret_cast<const unsigned int*>(xab);

    // segment bounds for the node's 4 type-buckets (contiguous in srows)
    const int4 pv = *reinterpret_cast<const int4*>(ptr + 4 * n);
    const int p4e = ptr[4 * n + 4];
    int seg[5];
    seg[0] = pv.x; seg[1] = pv.y; seg[2] = pv.z; seg[3] = pv.w; seg[4] = p4e;
    const int p0 = pv.x;

    // XB rows (b1 baked), per type
    float xbl[4], xbh[4];
    #pragma unroll
    for (int t = 0; t < 4; ++t) {
        unsigned int v = x32[((size_t)(2 * t + 1) * N_NODES + n) * 64 + lane];
        xbl[t] = bf2f_lo(v); xbh[t] = bf2f_hi(v);
    }

    float al[4] = {0.f, 0.f, 0.f, 0.f}, ah[4] = {0.f, 0.f, 0.f, 0.f};

    for (int co = p0; co < p4e; co += 64) {
        const int rem = p4e - co;
        // one chunk load: lane l holds srows[co + l] (clamped) — indices distributed via shfl
        const unsigned int cv = (unsigned int)srows[co + min(lane, rem - 1)];
        const int ce = co + 64;
        #pragma unroll
        for (int t = 0; t < 4; ++t) {
            const int lo = max(seg[t], co);
            const int hi = min(seg[t + 1], ce);
            for (int j = lo; j < hi; j += 4) {
                unsigned int vv[4];
                #pragma unroll
                for (int i = 0; i < 4; ++i) {
                    int pos = min(j + i, hi - 1) - co;
                    unsigned int absr = (unsigned int)__shfl((int)cv, pos, 64);
                    vv[i] = x32[(size_t)absr * 64 + lane];
                }
                #pragma unroll
                for (int i = 0; i < 4; ++i) {
                    bool on = (j + i) < hi;
                    float h0 = fmaxf(bf2f_lo(vv[i]) + xbl[t], 0.f);
                    float h1 = fmaxf(bf2f_hi(vv[i]) + xbh[t], 0.f);
                    al[t] += on ? h0 : 0.f;
                    ah[t] += on ? h1 : 0.f;
                }
            }
        }
    }

    unsigned int* S32 = reinterpret_cast<unsigned int*>(S);
    #pragma unroll
    for (int t = 0; t < 4; ++t)
        S32[((size_t)n * 4 + t) * 64 + lane] =
            (unsigned int)f2bf(al[t]) | ((unsigned int)f2bf(ah[t]) << 16);
}

// ---------------- GEMM2 (+self-proj) + ReLU + LayerNorm fused ----------------
// out[n] = LN(relu(x[n]@SW + sb + sum_t S_t[n] @ W2_t + sum_t cnt_{t,n} * b2_t))
__global__ __launch_bounds__(256, 2) void k_gemm2_ln(
    const unsigned short* __restrict__ S,      // node-major [n][4][128]
    const unsigned short* __restrict__ w2T,
    const unsigned short* __restrict__ wcatT,   // slab 8 = self weights
    const unsigned short* __restrict__ xb,
    const float* __restrict__ b2,
    const float* __restrict__ sb,
    const int* __restrict__ cnt,                // per (node*4+t) counts
    const float* __restrict__ gamma,
    const float* __restrict__ beta,
    float* __restrict__ out)
{
    const int nb = blockIdx.x * 128;
    __shared__ __align__(16) unsigned char sm[128 * 136 * 2 + 4 * 128 * 32 * 2 + 512 * 4];
    unsigned short* sS  = reinterpret_cast<unsigned short*>(sm);               // [128*136]
    unsigned short* sW2 = reinterpret_cast<unsigned short*>(sm + 34816);       // [4*128*32]
    float* sB2          = reinterpret_cast<float*>(sm + 34816 + 32768);        // [512]
    float* rows         = reinterpret_cast<float*>(sm);                        // [128][132] alias, post-MFMA

    const int tid = threadIdx.x;
    const int lane = tid & 63;
    const int w = tid >> 6;
    const int g = lane >> 4;
    const int c = lane & 15;
    const int wf = w >> 1;   // f half
    const int we = w & 1;    // n half

    sB2[tid] = b2[tid];
    sB2[tid + 256] = b2[tid + 256];

    f32x4 acc[4][4];
    #pragma unroll
    for (int ft = 0; ft < 4; ++ft)
        #pragma unroll
        for (int et = 0; et < 4; ++et)
            acc[ft][et] = f32x4{0.f, 0.f, 0.f, 0.f};

    for (int t = 0; t < 5; ++t) {
        const unsigned short* srcW = (t < 4) ? w2T + (size_t)t * 16384 : wcatT + (size_t)8 * 16384;
        __syncthreads();   // prev reads done before restage
        // stage input tile (coalesced, clamp)
        #pragma unroll
        for (int it = 0; it < 8; ++it) {
            int row = 16 * it + (tid >> 4);
            int node = min(nb + row, N_NODES - 1);
            const unsigned short* src = (t < 4)
                ? S + ((size_t)node * 4 + t) * 128
                : xb + (size_t)node * 128;
            const u16x8 v = *reinterpret_cast<const u16x8*>(src + (tid & 15) * 8);
            *reinterpret_cast<u16x8*>(&sS[row * 136 + (tid & 15) * 8]) = v;
        }
        {
            const u16x8* gsrc = reinterpret_cast<const u16x8*>(srcW);
            u16x8* ldst = reinterpret_cast<u16x8*>(sW2);
            #pragma unroll
            for (int it = 0; it < 8; ++it)
                ldst[tid + 256 * it] = gsrc[tid + 256 * it];
        }
        __syncthreads();
        #pragma unroll
        for (int ks = 0; ks < 4; ++ks) {
            bf16x8 af[4], bfr[4];
            #pragma unroll
            for (int ft = 0; ft < 4; ++ft)
                af[ft] = *reinterpret_cast<const bf16x8*>(&sW2[ks * 4096 + (64 * wf + 16 * ft + c) * 32 + 8 * g]);
            #pragma unroll
            for (int et = 0; et < 4; ++et)
                bfr[et] = *reinterpret_cast<const bf16x8*>(&sS[(64 * we + 16 * et + c) * 136 + ks * 32 + 8 * g]);
            #pragma unroll
            for (int ft = 0; ft < 4; ++ft)
                #pragma unroll
                for (int et = 0; et < 4; ++et)
                    acc[ft][et] = __builtin_amdgcn_mfma_f32_16x16x32_bf16(af[ft], bfr[et], acc[ft][et], 0, 0, 0);
        }
    }
    __syncthreads();   // MFMA reads of sS/sW2 done; rows[] may now overwrite them

    // epilogue: + sb + cnt*b2 -> rows[n][f] (fp32, stride 132)
    #pragma unroll
    for (int et = 0; et < 4; ++et) {
        int n = 64 * we + 16 * et + c;
        int node = nb + n;
        if (node >= N_NODES) continue;
        const int4 cv4 = *reinterpret_cast<const int4*>(cnt + node * 4);
        float cnt4[N_TYPES] = {(float)cv4.x, (float)cv4.y, (float)cv4.z, (float)cv4.w};
        #pragma unroll
        for (int ft = 0; ft < 4; ++ft) {
            int f0 = 64 * wf + 16 * ft + 4 * g;
            const float4 sbv = *reinterpret_cast<const float4*>(sb + f0);
            float v[4];
            v[0] = acc[ft][et][0] + sbv.x;
            v[1] = acc[ft][et][1] + sbv.y;
            v[2] = acc[ft][et][2] + sbv.z;
            v[3] = acc[ft][et][3] + sbv.w;
            #pragma unroll
            for (int r = 0; r < 4; ++r) {
                float bs = 0.f;
                #pragma unroll
                for (int t = 0; t < N_TYPES; ++t)
                    bs = fmaf(cnt4[t], sB2[t * 128 + f0 + r], bs);
                v[r] += bs;
            }
            *reinterpret_cast<float4*>(&rows[n * 132 + f0]) = *reinterpret_cast<float4*>(v);
        }
    }
    __syncthreads();

    // ReLU + LN: each wave handles 32 rows
    for (int rr = 0; rr < 32; ++rr) {
        int r = w * 32 + rr;
        int node = nb + r;
        if (node >= N_NODES) break;
        float2 v = *reinterpret_cast<float2*>(&rows[r * 132 + lane * 2]);
        v.x = fmaxf(v.x, 0.f);
        v.y = fmaxf(v.y, 0.f);
        float s = v.x + v.y;
        float ss = v.x * v.x + v.y * v.y;
        #pragma unroll
        for (int m = 1; m < 64; m <<= 1) {
            s  += __shfl_xor(s, m, 64);
            ss += __shfl_xor(ss, m, 64);
        }
        float mu = s * (1.f / 128.f);
        float var = ss * (1.f / 128.f) - mu * mu;
        float rs = rsqrtf(var + LN_EPS);
        const float2 gm = *reinterpret_cast<const float2*>(gamma + lane * 2);
        const float2 bt = *reinterpret_cast<const float2*>(beta + lane * 2);
        float2 o;
        o.x = (v.x - mu) * rs * gm.x + bt.x;
        o.y = (v.y - mu) * rs * gm.y + bt.y;
        *reinterpret_cast<float2*>(out + (size_t)node * D_OUT + lane * 2) = o;
    }
}

extern "C" void kernel_launch(void* const* d_in, const int* in_sizes, int n_in,
                              void* d_out, int out_size, void* d_ws, size_t ws_size,
                              hipStream_t stream) {
    const float* x     = (const float*)d_in[0];
    const int*   ei    = (const int*)d_in[1];
    const int*   attr  = (const int*)d_in[2];
    const float* w1    = (const float*)d_in[3];
    const float* b1    = (const float*)d_in[4];
    const float* w2    = (const float*)d_in[5];
    const float* b2    = (const float*)d_in[6];
    const float* sw    = (const float*)d_in[7];
    const float* sb    = (const float*)d_in[8];
    const float* gamma = (const float*)d_in[9];
    const float* beta  = (const float*)d_in[10];
    float* out = (float*)d_out;

    if (ws_size < WS_TOTAL) return;   // fail visibly rather than corrupt

    char* ws = (char*)d_ws;
    int* cnt    = (int*)(ws + OFF_CNT);
    int* ptr    = (int*)(ws + OFF_PTR);
    int* cursor = (int*)(ws + OFF_CUR);
    int* bsum   = (int*)(ws + OFF_BSUM);
    int* srows  = (int*)(ws + OFF_SROWS);
    unsigned short* xb    = (unsigned short*)(ws + OFF_XB);
    unsigned short* wcatT = (unsigned short*)(ws + OFF_WCAT);
    float*          bias  = (float*)(ws + OFF_BIAS);
    unsigned short* w2T   = (unsigned short*)(ws + OFF_W2T);
    unsigned short* xab   = (unsigned short*)(ws + OFF_XABC);
    unsigned short* S     = (unsigned short*)(ws + OFF_S);

    hipMemsetAsync(cnt, 0, (size_t)N_BUCKETS * 4, stream);

    k_prep_all<<<NB_CVT + NB_PREP + NB_HIST, 256, 0, stream>>>(
        x, w1, sw, b1, sb, w2, ei, attr, xb, wcatT, bias, w2T, cnt);

    k_scanA<<<NSB, 256, 0, stream>>>(cnt, bsum);
    k_scanC<<<NSB, 256, 0, stream>>>(cnt, bsum, ptr, cursor);
    k_scatter2<<<(N_EDGES + 255) / 256, 256, 0, stream>>>(ei, attr, cursor, srows);

    k_gemm1<<<dim3((N_NODES + 127) / 128, 8), 256, 0, stream>>>(xb, wcatT, bias, xab);
    k_agg<<<(N_NODES * 64 + 255) / 256, 256, 0, stream>>>(xab, ptr, srows, S);
    k_gemm2_ln<<<(N_NODES + 127) / 128, 256, 0, stream>>>(
        S, w2T, wcatT, xb, b2, sb, cnt, gamma, beta, out);
}